// Round 2
// baseline (2743.582 us; speedup 1.0000x reference)
//
#include <hip/hip_runtime.h>
#include <stdint.h>

#define NN   50000
#define NE   1600000
#define DIN  128
#define DMID 256
#define DOUT 128
#define NMID 8
// edge lists padded to multiple of 8 with sentinel src = NN (zero row in gs)
#define PADCAP (NE + 7 * NN)

#define AS1 __attribute__((address_space(1)))
#define AS3 __attribute__((address_space(3)))

typedef unsigned short u16;
typedef unsigned int   u32;
typedef __attribute__((ext_vector_type(8))) short short8;
typedef __attribute__((ext_vector_type(4))) float f32x4;
typedef __attribute__((ext_vector_type(2))) float f32x2;
typedef __attribute__((ext_vector_type(4))) int i32x4;

__device__ __forceinline__ float bf2f(u32 u) {
    union { u32 i; float f; } c; c.i = u << 16; return c.f;
}
__device__ __forceinline__ float ubf_lo(u32 v) {
    union { u32 i; float f; } c; c.i = v << 16; return c.f;
}
__device__ __forceinline__ float ubf_hi(u32 v) {
    union { u32 i; float f; } c; c.i = v & 0xffff0000u; return c.f;
}
__device__ __forceinline__ u16 f2bf(float f) {
    union { float f; u32 i; } c; c.f = f;
    u32 u = c.i;
    return (u16)((u + 0x7fffu + ((u >> 16) & 1u)) >> 16);
}
__device__ __forceinline__ void split2(float v, u16& hi, u16& lo) {
    hi = f2bf(v);
    float r = v - bf2f(hi);
    lo = f2bf(r);
}

// ---------------- preprocessing ----------------
// pass 1: per-edge rank within its dst bucket; counts[] = true degree after.
__global__ void rank_kernel(const int* __restrict__ ei, int* __restrict__ counts,
                            int* __restrict__ rank) {
    int i = (blockIdx.x * blockDim.x + threadIdx.x) * 4;
    if (i < NE) {
        i32x4 d = *(const i32x4*)(ei + NE + i);
        i32x4 r;
        r.x = atomicAdd(&counts[d.x], 1);
        r.y = atomicAdd(&counts[d.y], 1);
        r.z = atomicAdd(&counts[d.z], 1);
        r.w = atomicAdd(&counts[d.w], 1);
        *(i32x4*)(rank + i) = r;
    }
}

// dinv from true degree; cpad = degree padded to multiple of 8.
__global__ void pad_kernel(const int* __restrict__ counts, int* __restrict__ cpad,
                           float* __restrict__ dinv) {
    int i = blockIdx.x * blockDim.x + threadIdx.x;
    if (i < NN) {
        int c = counts[i];
        dinv[i] = rsqrtf((float)c + 1.0f);
        cpad[i] = (c + 7) & ~7;
    }
}

__global__ __launch_bounds__(1024) void scan_kernel(const int* __restrict__ cpad,
                                                    int* __restrict__ rowp) {
    __shared__ int sh[1024];
    const int t = threadIdx.x;
    constexpr int ITEMS = (NN + 1023) / 1024;  // 49
    const int start = t * ITEMS;
    int sum = 0;
    for (int j = 0; j < ITEMS; ++j) {
        int idx = start + j;
        if (idx < NN) sum += cpad[idx];
    }
    sh[t] = sum;
    __syncthreads();
    for (int offs = 1; offs < 1024; offs <<= 1) {
        int v = (t >= offs) ? sh[t - offs] : 0;
        __syncthreads();
        sh[t] += v;
        __syncthreads();
    }
    int base = (t == 0) ? 0 : sh[t - 1];
    for (int j = 0; j < ITEMS; ++j) {
        int idx = start + j;
        if (idx < NN) {
            rowp[idx] = base;
            base += cpad[idx];
            if (idx == NN - 1) rowp[NN] = base;   // padded total
        }
    }
}

// prefill srcs (u16) with sentinel node NN (its gs row is zero in every slice).
__global__ void fill16_kernel(u16* __restrict__ srcs) {
    int i = (blockIdx.x * blockDim.x + threadIdx.x) * 8;
    if (i < PADCAP) {
        const int v = NN | (NN << 16);
        *(i32x4*)(srcs + i) = (i32x4){v, v, v, v};
    }
}

// pass 2: scatter src ids (u16) into CSR slots (no atomics).
__global__ void scatter16_kernel(const int* __restrict__ ei, const int* __restrict__ rowp,
                                 const int* __restrict__ rank, u16* __restrict__ srcs) {
    int i = (blockIdx.x * blockDim.x + threadIdx.x) * 4;
    if (i < NE) {
        i32x4 d = *(const i32x4*)(ei + NE + i);
        i32x4 s = *(const i32x4*)(ei + i);
        i32x4 r = *(const i32x4*)(rank + i);
        srcs[rowp[d.x] + r.x] = (u16)s.x;
        srcs[rowp[d.y] + r.y] = (u16)s.y;
        srcs[rowp[d.z] + r.z] = (u16)s.z;
        srcs[rowp[d.w] + r.w] = (u16)s.w;
    }
}

// zero the sentinel row (node NN) of each of the 8 slices of gs.
__global__ void zsent_kernel(u16* __restrict__ gs) {
    int s = threadIdx.x >> 5, c = threadIdx.x & 31;
    gs[((size_t)s * (NN + 1) + NN) * 32 + c] = 0;
}

// W [K x Dc] fp32 row-major -> slice-major bf16 split: Whi[((k/32)*Dc + d)*32 + k%32]
__global__ void wsplit_kernel(const float* __restrict__ W, u16* __restrict__ Whi,
                              u16* __restrict__ Wlo, int K, int Dc) {
    int idx = blockIdx.x * blockDim.x + threadIdx.x;
    if (idx < K * Dc) {
        int k = idx / Dc, d = idx - k * Dc;
        u16 hi, lo;
        split2(W[idx], hi, lo);
        size_t o = ((size_t)(k >> 5) * Dc + d) * 32 + (k & 31);
        Whi[o] = hi;
        Wlo[o] = lo;
    }
}

// x [NN][128] fp32 -> row-major bf16 hi/lo
__global__ void xsplit_kernel(const float* __restrict__ x, u16* __restrict__ xhi,
                              u16* __restrict__ xlo) {
    int i = blockIdx.x * blockDim.x + threadIdx.x;
    int stride = gridDim.x * blockDim.x;
    for (; i < NN * DIN; i += stride) {
        u16 hi, lo;
        split2(x[i], hi, lo);
        xhi[i] = hi;
        xlo[i] = lo;
    }
}

// ---------------- GEMM: gs = sliced((x @ W) * dinv[row]) -------------------
// gs layout: [slice][node(+1)][32] bf16 — feature-column-blocked so the agg
// gather per slice has a 3.2 MB working set (fits one XCD's 4 MB L2).
template <int K, int Dc>
__global__ __launch_bounds__(512, 4) void gemm_kernel(const u16* __restrict__ xhi,
                                                      const u16* __restrict__ xlo,
                                                      const u16* __restrict__ whi,
                                                      const u16* __restrict__ wlo,
                                                      const float* __restrict__ dinv,
                                                      u16* __restrict__ gs) {
    constexpr int NTW = Dc / 32;
    constexpr int KS = K / 32;
    __shared__ u16 bh[Dc * 32];
    __shared__ u16 bl[Dc * 32];
    const int tid = threadIdx.x;
    const int wid = tid >> 6;
    const int rowPanel = wid >> 1;
    const int colPanel = wid & 1;
    const int lane = tid & 63;
    const int m = lane & 15, quad = lane >> 4;
    const int rowBase = blockIdx.x * 128 + rowPanel * 32;

    f32x4 acc[2][NTW];
#pragma unroll
    for (int rg = 0; rg < 2; ++rg)
#pragma unroll
        for (int t = 0; t < NTW; ++t) acc[rg][t] = (f32x4){0.f, 0.f, 0.f, 0.f};

    size_t arow[2];
#pragma unroll
    for (int rg = 0; rg < 2; ++rg) {
        int rowA = rowBase + rg * 16 + m;
        if (rowA > NN - 1) rowA = NN - 1;
        arow[rg] = (size_t)rowA * K + quad * 8;
    }

    for (int ks = 0; ks < KS; ++ks) {
        const u16* sh_src = whi + (size_t)ks * Dc * 32;
        const u16* sl_src = wlo + (size_t)ks * Dc * 32;
        __syncthreads();
#pragma unroll
        for (int i = 0; i < Dc * 4; i += 512) {
            int j = i + tid;
            __builtin_amdgcn_global_load_lds((const AS1 void*)(sh_src + j * 8),
                                             (AS3 void*)((AS3 u16*)bh + j * 8), 16, 0, 0);
            __builtin_amdgcn_global_load_lds((const AS1 void*)(sl_src + j * 8),
                                             (AS3 void*)((AS3 u16*)bl + j * 8), 16, 0, 0);
        }
        short8 ah[2], al[2];
#pragma unroll
        for (int rg = 0; rg < 2; ++rg) {
            ah[rg] = *(const short8*)(xhi + arow[rg] + ks * 32);
            al[rg] = *(const short8*)(xlo + arow[rg] + ks * 32);
        }
        __syncthreads();
#pragma unroll
        for (int t = 0; t < NTW; ++t) {
            const int bo = ((colPanel * NTW + t) * 16 + m) * 32 + quad * 8;
            short8 wh = *(const short8*)(bh + bo);
            short8 wl = *(const short8*)(bl + bo);
#pragma unroll
            for (int rg = 0; rg < 2; ++rg) {
                acc[rg][t] = __builtin_amdgcn_mfma_f32_16x16x32_bf16(ah[rg], wh, acc[rg][t], 0, 0, 0);
                acc[rg][t] = __builtin_amdgcn_mfma_f32_16x16x32_bf16(al[rg], wh, acc[rg][t], 0, 0, 0);
                acc[rg][t] = __builtin_amdgcn_mfma_f32_16x16x32_bf16(ah[rg], wl, acc[rg][t], 0, 0, 0);
            }
        }
    }

#pragma unroll
    for (int rg = 0; rg < 2; ++rg) {
        const int r0 = rowBase + rg * 16 + quad * 4;
        float dv[4];
#pragma unroll
        for (int r = 0; r < 4; ++r) {
            int rr = r0 + r;
            dv[r] = (rr < NN) ? dinv[rr] : 0.f;
        }
#pragma unroll
        for (int t = 0; t < NTW; ++t) {
            const int col = colPanel * (Dc / 2) + t * 16 + m;
#pragma unroll
            for (int r = 0; r < 4; ++r) {
                int rr = r0 + r;
                if (rr < NN) {
                    size_t o = ((size_t)(col >> 5) * (NN + 1) + rr) * 32 + (col & 31);
                    gs[o] = f2bf(acc[rg][t][r] * dv[r]);
                }
            }
        }
    }
}

// ---------------- sliced aggregation -----------------------------------------
// Block = (slice, 4-node group), slice = blockIdx & (NSL-1). With round-robin
// block->XCD dispatch, each XCD gathers only from its own 3.2 MB slice of gs
// -> L2-resident gather. Wave per node; 4 edge-groups of 16 lanes; lane owns
// 2 features (u32 = 2 bf16). Writes pre-LN v (fp32, sliced) + per-slice
// (sum, sumsq) partials; LN/SiLU happens in ln_kernel.

__device__ __forceinline__ void loadS(const u16* __restrict__ srcs, int eo, int (&S)[8]) {
    i32x4 v = *(const i32x4*)(srcs + eo);
    S[0] = v.x & 0xffff; S[1] = (v.x >> 16) & 0xffff;
    S[2] = v.y & 0xffff; S[3] = (v.y >> 16) & 0xffff;
    S[4] = v.z & 0xffff; S[5] = (v.z >> 16) & 0xffff;
    S[6] = v.w & 0xffff; S[7] = (v.w >> 16) & 0xffff;
}

template <int Dc, bool FINAL>
__global__ __launch_bounds__(256) void agg_kernel(const u16* __restrict__ gs,
                                                  const int* __restrict__ rowp,
                                                  const u16* __restrict__ srcs,
                                                  const float* __restrict__ dinv,
                                                  const float* __restrict__ bias,
                                                  float* __restrict__ vs,
                                                  float* __restrict__ part,
                                                  float* __restrict__ outf) {
    constexpr int NSL = Dc / 32;
    constexpr int SH = (NSL == 8) ? 3 : 2;
    const int slice = blockIdx.x & (NSL - 1);
    const int grp = blockIdx.x >> SH;
    const int wid = threadIdx.x >> 6, lane = threadIdx.x & 63;
    const int node = grp * 4 + wid;
    const int eg = lane >> 4, cs = lane & 15;

    // u32 view of this slice; +cs selects the lane's feature pair.
    const u32* gsl = (const u32*)gs + (size_t)slice * (NN + 1) * 16 + cs;

    float a0, a1;
    {   // self term, counted once (eg 0 only)
        u32 v = gsl[node * 16];
        a0 = (eg == 0) ? ubf_lo(v) : 0.f;
        a1 = (eg == 0) ? ubf_hi(v) : 0.f;
    }

    const int e0 = rowp[node];
    const int nb = (rowp[node + 1] - e0) >> 3;   // padded: whole batches of 8

    if (nb > 0) {
        const int last = e0 + (nb - 1) * 8;      // clamp target (dup-safe re-issue)
        int S[8];
        u32 A0, A1, B0, B1;
        loadS(srcs, e0, S);
        A0 = gsl[S[eg] * 16]; A1 = gsl[S[eg + 4] * 16];
        loadS(srcs, nb > 1 ? e0 + 8 : e0, S);
        int b = 0;
        for (;;) {
            B0 = gsl[S[eg] * 16]; B1 = gsl[S[eg + 4] * 16];  // batch b+1
            int ec = e0 + (b + 2) * 8;
            ec = ec > last ? last : ec;
            loadS(srcs, ec, S);                               // srcs batch b+2
            a0 += ubf_lo(A0) + ubf_lo(A1);                    // consume batch b
            a1 += ubf_hi(A0) + ubf_hi(A1);
            if (b + 1 >= nb) break;
            A0 = gsl[S[eg] * 16]; A1 = gsl[S[eg + 4] * 16];   // batch b+2
            ec = e0 + (b + 3) * 8;
            ec = ec > last ? last : ec;
            loadS(srcs, ec, S);                               // srcs batch b+3
            a0 += ubf_lo(B0) + ubf_lo(B1);                    // consume batch b+1
            a1 += ubf_hi(B0) + ubf_hi(B1);
            if (b + 2 >= nb) break;
            b += 2;
        }
    }

    // reduce across the 4 edge-groups (lanes with equal cs)
    a0 += __shfl_xor(a0, 16, 64); a0 += __shfl_xor(a0, 32, 64);
    a1 += __shfl_xor(a1, 16, 64); a1 += __shfl_xor(a1, 32, 64);

    const float dv = dinv[node];
    const int f = slice * 32 + cs * 2;
    const float v0 = a0 * dv + bias[f];
    const float v1 = a1 * dv + bias[f + 1];

    if (FINAL) {
        if (eg == 0) *(f32x2*)(outf + (size_t)node * Dc + f) = (f32x2){v0, v1};
    } else {
        if (eg == 0)
            *(f32x2*)(vs + ((size_t)slice * NN + node) * 32 + cs * 2) = (f32x2){v0, v1};
        float p1 = v0 + v1, p2 = v0 * v0 + v1 * v1;
        p1 += __shfl_xor(p1, 1, 64); p2 += __shfl_xor(p2, 1, 64);
        p1 += __shfl_xor(p1, 2, 64); p2 += __shfl_xor(p2, 2, 64);
        p1 += __shfl_xor(p1, 4, 64); p2 += __shfl_xor(p2, 4, 64);
        p1 += __shfl_xor(p1, 8, 64); p2 += __shfl_xor(p2, 8, 64);
        if (lane == 0)
            *(f32x2*)(part + ((size_t)node * NSL + slice) * 2) = (f32x2){p1, p2};
    }
}

// ---------------- LN + SiLU + bf16 hi/lo split (streaming) -------------------
// wave per node; lane owns 4 consecutive features. Reads sliced v + partials.
__global__ __launch_bounds__(256) void ln_kernel(const float* __restrict__ vs,
                                                 const float* __restrict__ part,
                                                 const float* __restrict__ gamma,
                                                 const float* __restrict__ beta,
                                                 u16* __restrict__ xhi,
                                                 u16* __restrict__ xlo) {
    const int wid = threadIdx.x >> 6, lane = threadIdx.x & 63;
    const int node = blockIdx.x * 4 + wid;
    const int s = lane >> 3, o = (lane & 7) * 4;

    f32x4 vv = *(const f32x4*)(vs + ((size_t)s * NN + node) * 32 + o);
    f32x2 p = *(const f32x2*)(part + ((size_t)node * 8 + (lane & 7)) * 2);
    float s1 = p.x, s2 = p.y;
    s1 += __shfl_xor(s1, 1, 64); s2 += __shfl_xor(s2, 1, 64);
    s1 += __shfl_xor(s1, 2, 64); s2 += __shfl_xor(s2, 2, 64);
    s1 += __shfl_xor(s1, 4, 64); s2 += __shfl_xor(s2, 4, 64);

    const float mu = s1 * (1.f / 256.f);
    const float var = s2 * (1.f / 256.f) - mu * mu;
    const float rstd = rsqrtf(fmaxf(var, 0.f) + 1e-5f);

    const int f = s * 32 + o;
    u16 hh[4], ll[4];
#pragma unroll
    for (int j = 0; j < 4; ++j) {
        float y = (vv[j] - mu) * rstd * gamma[f + j] + beta[f + j];
        y = y / (1.f + __expf(-y));
        split2(y, hh[j], ll[j]);
    }
    uint2 oh, ol;
    oh.x = (u32)hh[0] | ((u32)hh[1] << 16);
    oh.y = (u32)hh[2] | ((u32)hh[3] << 16);
    ol.x = (u32)ll[0] | ((u32)ll[1] << 16);
    ol.y = (u32)ll[2] | ((u32)ll[3] << 16);
    *(uint2*)(xhi + (size_t)node * 256 + f) = oh;
    *(uint2*)(xlo + (size_t)node * 256 + f) = ol;
}

// ---------------- launcher ----------------

extern "C" void kernel_launch(void* const* d_in, const int* in_sizes, int n_in,
                              void* d_out, int out_size, void* d_ws, size_t ws_size,
                              hipStream_t stream) {
    (void)in_sizes; (void)n_in; (void)out_size; (void)ws_size;
    const float* x_in  = (const float*)d_in[0];
    const int*   ei    = (const int*)d_in[1];
    const float* W_in  = (const float*)d_in[2];
    const float* b_in  = (const float*)d_in[3];
    const float* W_mid = (const float*)d_in[4];
    const float* b_mid = (const float*)d_in[5];
    const float* W_out = (const float*)d_in[6];
    const float* b_out = (const float*)d_in[7];
    const float* gamma = (const float*)d_in[8];
    const float* beta  = (const float*)d_in[9];

    char* ws = (char*)d_ws;
    size_t off = 0;
    auto alloc = [&](size_t bytes) -> char* {
        char* p = ws + off;
        off += (bytes + 255) & ~(size_t)255;
        return p;
    };
    float* dinv   = (float*)alloc((size_t)NN * 4);
    int* counts   = (int*)alloc((size_t)NN * 4);
    int* cpad     = (int*)alloc((size_t)NN * 4);
    int* rowp     = (int*)alloc((size_t)(NN + 1) * 4);
    int* rank     = (int*)alloc((size_t)NE * 4);
    u16* srcs     = (u16*)alloc((size_t)PADCAP * 2);
    u16* whi_in   = (u16*)alloc((size_t)DIN * DMID * 2);
    u16* wlo_in   = (u16*)alloc((size_t)DIN * DMID * 2);
    u16* whi_mid  = (u16*)alloc((size_t)NMID * DMID * DMID * 2);
    u16* wlo_mid  = (u16*)alloc((size_t)NMID * DMID * DMID * 2);
    u16* whi_out  = (u16*)alloc((size_t)DMID * DOUT * 2);
    u16* wlo_out  = (u16*)alloc((size_t)DMID * DOUT * 2);
    u16* xhi      = (u16*)alloc((size_t)NN * DMID * 2);
    u16* xlo      = (u16*)alloc((size_t)NN * DMID * 2);
    u16* gs       = (u16*)alloc((size_t)8 * (NN + 1) * 32 * 2);  // sliced g
    float* vs     = (float*)alloc((size_t)NN * DMID * 4);        // pre-LN v, sliced
    float* part   = (float*)alloc((size_t)NN * 8 * 2 * 4);       // (sum, sumsq)

    hipMemsetAsync(counts, 0, (size_t)NN * 4, stream);

    const int EB4 = (NE / 4 + 255) / 256;       // 1563
    const int NBK = (NN + 255) / 256;           // 196
    rank_kernel<<<EB4, 256, 0, stream>>>(ei, counts, rank);
    pad_kernel<<<NBK, 256, 0, stream>>>(counts, cpad, dinv);
    scan_kernel<<<1, 1024, 0, stream>>>(cpad, rowp);
    fill16_kernel<<<(PADCAP / 8 + 255) / 256, 256, 0, stream>>>(srcs);
    scatter16_kernel<<<EB4, 256, 0, stream>>>(ei, rowp, rank, srcs);
    zsent_kernel<<<1, 256, 0, stream>>>(gs);

    wsplit_kernel<<<(DIN * DMID + 255) / 256, 256, 0, stream>>>(W_in, whi_in, wlo_in, DIN, DMID);
    for (int i = 0; i < NMID; ++i)
        wsplit_kernel<<<(DMID * DMID + 255) / 256, 256, 0, stream>>>(
            W_mid + (size_t)i * DMID * DMID, whi_mid + (size_t)i * DMID * DMID,
            wlo_mid + (size_t)i * DMID * DMID, DMID, DMID);
    wsplit_kernel<<<(DMID * DOUT + 255) / 256, 256, 0, stream>>>(W_out, whi_out, wlo_out, DMID, DOUT);
    xsplit_kernel<<<1024, 256, 0, stream>>>(x_in, xhi, xlo);

    const int GB = (NN + 127) / 128;            // 391 (8 waves/block)
    const int AGM = (NN / 4) * 8;               // 100000 blocks: 8 slices x node-groups
    const int AGF = (NN / 4) * 4;               // 50000 blocks: 4 slices
    const int LNB = NN / 4;                     // 12500

    // layer 0: 128 -> 256
    gemm_kernel<DIN, DMID><<<GB, 512, 0, stream>>>(xhi, xlo, whi_in, wlo_in, dinv, gs);
    agg_kernel<DMID, false><<<AGM, 256, 0, stream>>>(gs, rowp, srcs, dinv, b_in,
                                                     vs, part, nullptr);
    ln_kernel<<<LNB, 256, 0, stream>>>(vs, part, gamma, beta, xhi, xlo);
    // 8 mid layers: 256 -> 256
    for (int i = 0; i < NMID; ++i) {
        gemm_kernel<DMID, DMID><<<GB, 512, 0, stream>>>(xhi, xlo,
                                                        whi_mid + (size_t)i * DMID * DMID,
                                                        wlo_mid + (size_t)i * DMID * DMID,
                                                        dinv, gs);
        agg_kernel<DMID, false><<<AGM, 256, 0, stream>>>(gs, rowp, srcs, dinv,
                                                         b_mid + (size_t)i * DMID,
                                                         vs, part, nullptr);
        ln_kernel<<<LNB, 256, 0, stream>>>(vs, part,
                                           gamma + (size_t)(i + 1) * DMID,
                                           beta + (size_t)(i + 1) * DMID, xhi, xlo);
    }
    // final layer: 256 -> 128, no LN/SiLU; writes fp32 out directly
    gemm_kernel<DMID, DOUT><<<GB, 512, 0, stream>>>(xhi, xlo, whi_out, wlo_out, dinv, gs);
    agg_kernel<DOUT, true><<<AGF, 256, 0, stream>>>(gs, rowp, srcs, dinv, b_out,
                                                    nullptr, nullptr, (float*)d_out);
}

// Round 3
// 2314.081 us; speedup vs baseline: 1.1856x; 1.1856x over previous
//
#include <hip/hip_runtime.h>
#include <stdint.h>

#define NN   50000
#define NE   1600000
#define DIN  128
#define DMID 256
#define DOUT 128
#define NMID 8
// edge lists padded to multiple of 8 with sentinel src = NN (zero row in gs)
#define PADCAP (NE + 7 * NN)

#define AS1 __attribute__((address_space(1)))
#define AS3 __attribute__((address_space(3)))

typedef unsigned short u16;
typedef unsigned int   u32;
typedef __attribute__((ext_vector_type(8))) short short8;
typedef __attribute__((ext_vector_type(4))) float f32x4;
typedef __attribute__((ext_vector_type(2))) float f32x2;
typedef __attribute__((ext_vector_type(4))) int i32x4;

__device__ __forceinline__ float bf2f(u32 u) {
    union { u32 i; float f; } c; c.i = u << 16; return c.f;
}
__device__ __forceinline__ float ubf_lo(u32 v) {
    union { u32 i; float f; } c; c.i = v << 16; return c.f;
}
__device__ __forceinline__ float ubf_hi(u32 v) {
    union { u32 i; float f; } c; c.i = v & 0xffff0000u; return c.f;
}
__device__ __forceinline__ u16 f2bf(float f) {
    union { float f; u32 i; } c; c.f = f;
    u32 u = c.i;
    return (u16)((u + 0x7fffu + ((u >> 16) & 1u)) >> 16);
}
__device__ __forceinline__ void split2(float v, u16& hi, u16& lo) {
    hi = f2bf(v);
    float r = v - bf2f(hi);
    lo = f2bf(r);
}

// ---------------- preprocessing ----------------
// pass 1: per-edge rank within its dst bucket; counts[] = true degree after.
__global__ void rank_kernel(const int* __restrict__ ei, int* __restrict__ counts,
                            int* __restrict__ rank) {
    int i = (blockIdx.x * blockDim.x + threadIdx.x) * 4;
    if (i < NE) {
        i32x4 d = *(const i32x4*)(ei + NE + i);
        i32x4 r;
        r.x = atomicAdd(&counts[d.x], 1);
        r.y = atomicAdd(&counts[d.y], 1);
        r.z = atomicAdd(&counts[d.z], 1);
        r.w = atomicAdd(&counts[d.w], 1);
        *(i32x4*)(rank + i) = r;
    }
}

// dinv from true degree; cpad = degree padded to multiple of 8.
__global__ void pad_kernel(const int* __restrict__ counts, int* __restrict__ cpad,
                           float* __restrict__ dinv) {
    int i = blockIdx.x * blockDim.x + threadIdx.x;
    if (i < NN) {
        int c = counts[i];
        dinv[i] = rsqrtf((float)c + 1.0f);
        cpad[i] = (c + 7) & ~7;
    }
}

__global__ __launch_bounds__(1024) void scan_kernel(const int* __restrict__ cpad,
                                                    int* __restrict__ rowp) {
    __shared__ int sh[1024];
    const int t = threadIdx.x;
    constexpr int ITEMS = (NN + 1023) / 1024;  // 49
    const int start = t * ITEMS;
    int sum = 0;
    for (int j = 0; j < ITEMS; ++j) {
        int idx = start + j;
        if (idx < NN) sum += cpad[idx];
    }
    sh[t] = sum;
    __syncthreads();
    for (int offs = 1; offs < 1024; offs <<= 1) {
        int v = (t >= offs) ? sh[t - offs] : 0;
        __syncthreads();
        sh[t] += v;
        __syncthreads();
    }
    int base = (t == 0) ? 0 : sh[t - 1];
    for (int j = 0; j < ITEMS; ++j) {
        int idx = start + j;
        if (idx < NN) {
            rowp[idx] = base;
            base += cpad[idx];
            if (idx == NN - 1) rowp[NN] = base;   // padded total
        }
    }
}

// prefill srcs (u16) with sentinel node NN (its gs row is zero in every slice).
__global__ void fill16_kernel(u16* __restrict__ srcs) {
    int i = (blockIdx.x * blockDim.x + threadIdx.x) * 8;
    if (i < PADCAP) {
        const int v = NN | (NN << 16);
        *(i32x4*)(srcs + i) = (i32x4){v, v, v, v};
    }
}

// pass 2: scatter src ids (u16) into CSR slots (no atomics).
__global__ void scatter16_kernel(const int* __restrict__ ei, const int* __restrict__ rowp,
                                 const int* __restrict__ rank, u16* __restrict__ srcs) {
    int i = (blockIdx.x * blockDim.x + threadIdx.x) * 4;
    if (i < NE) {
        i32x4 d = *(const i32x4*)(ei + NE + i);
        i32x4 s = *(const i32x4*)(ei + i);
        i32x4 r = *(const i32x4*)(rank + i);
        srcs[rowp[d.x] + r.x] = (u16)s.x;
        srcs[rowp[d.y] + r.y] = (u16)s.y;
        srcs[rowp[d.z] + r.z] = (u16)s.z;
        srcs[rowp[d.w] + r.w] = (u16)s.w;
    }
}

// zero the sentinel row (node NN) of each of the 8 slices of gs.
__global__ void zsent_kernel(u16* __restrict__ gs) {
    int s = threadIdx.x >> 5, c = threadIdx.x & 31;
    gs[((size_t)s * (NN + 1) + NN) * 32 + c] = 0;
}

// W [K x Dc] fp32 row-major -> slice-major bf16 split: Whi[((k/32)*Dc + d)*32 + k%32]
__global__ void wsplit_kernel(const float* __restrict__ W, u16* __restrict__ Whi,
                              u16* __restrict__ Wlo, int K, int Dc) {
    int idx = blockIdx.x * blockDim.x + threadIdx.x;
    if (idx < K * Dc) {
        int k = idx / Dc, d = idx - k * Dc;
        u16 hi, lo;
        split2(W[idx], hi, lo);
        size_t o = ((size_t)(k >> 5) * Dc + d) * 32 + (k & 31);
        Whi[o] = hi;
        Wlo[o] = lo;
    }
}

// x [NN][128] fp32 -> row-major bf16 hi/lo
__global__ void xsplit_kernel(const float* __restrict__ x, u16* __restrict__ xhi,
                              u16* __restrict__ xlo) {
    int i = blockIdx.x * blockDim.x + threadIdx.x;
    int stride = gridDim.x * blockDim.x;
    for (; i < NN * DIN; i += stride) {
        u16 hi, lo;
        split2(x[i], hi, lo);
        xhi[i] = hi;
        xlo[i] = lo;
    }
}

// ---------------- GEMM: gs = sliced((x @ W) * dinv[row]) -------------------
// gs layout: [slice][node(+1)][32] bf16 — feature-column-blocked so the agg
// gather per slice has a 3.2 MB working set (fits one XCD's 4 MB L2).
template <int K, int Dc>
__global__ __launch_bounds__(512, 4) void gemm_kernel(const u16* __restrict__ xhi,
                                                      const u16* __restrict__ xlo,
                                                      const u16* __restrict__ whi,
                                                      const u16* __restrict__ wlo,
                                                      const float* __restrict__ dinv,
                                                      u16* __restrict__ gs) {
    constexpr int NTW = Dc / 32;
    constexpr int KS = K / 32;
    __shared__ u16 bh[Dc * 32];
    __shared__ u16 bl[Dc * 32];
    const int tid = threadIdx.x;
    const int wid = tid >> 6;
    const int rowPanel = wid >> 1;
    const int colPanel = wid & 1;
    const int lane = tid & 63;
    const int m = lane & 15, quad = lane >> 4;
    const int rowBase = blockIdx.x * 128 + rowPanel * 32;

    f32x4 acc[2][NTW];
#pragma unroll
    for (int rg = 0; rg < 2; ++rg)
#pragma unroll
        for (int t = 0; t < NTW; ++t) acc[rg][t] = (f32x4){0.f, 0.f, 0.f, 0.f};

    size_t arow[2];
#pragma unroll
    for (int rg = 0; rg < 2; ++rg) {
        int rowA = rowBase + rg * 16 + m;
        if (rowA > NN - 1) rowA = NN - 1;
        arow[rg] = (size_t)rowA * K + quad * 8;
    }

    for (int ks = 0; ks < KS; ++ks) {
        const u16* sh_src = whi + (size_t)ks * Dc * 32;
        const u16* sl_src = wlo + (size_t)ks * Dc * 32;
        __syncthreads();
#pragma unroll
        for (int i = 0; i < Dc * 4; i += 512) {
            int j = i + tid;
            __builtin_amdgcn_global_load_lds((const AS1 void*)(sh_src + j * 8),
                                             (AS3 void*)((AS3 u16*)bh + j * 8), 16, 0, 0);
            __builtin_amdgcn_global_load_lds((const AS1 void*)(sl_src + j * 8),
                                             (AS3 void*)((AS3 u16*)bl + j * 8), 16, 0, 0);
        }
        short8 ah[2], al[2];
#pragma unroll
        for (int rg = 0; rg < 2; ++rg) {
            ah[rg] = *(const short8*)(xhi + arow[rg] + ks * 32);
            al[rg] = *(const short8*)(xlo + arow[rg] + ks * 32);
        }
        __syncthreads();
#pragma unroll
        for (int t = 0; t < NTW; ++t) {
            const int bo = ((colPanel * NTW + t) * 16 + m) * 32 + quad * 8;
            short8 wh = *(const short8*)(bh + bo);
            short8 wl = *(const short8*)(bl + bo);
#pragma unroll
            for (int rg = 0; rg < 2; ++rg) {
                acc[rg][t] = __builtin_amdgcn_mfma_f32_16x16x32_bf16(ah[rg], wh, acc[rg][t], 0, 0, 0);
                acc[rg][t] = __builtin_amdgcn_mfma_f32_16x16x32_bf16(al[rg], wh, acc[rg][t], 0, 0, 0);
                acc[rg][t] = __builtin_amdgcn_mfma_f32_16x16x32_bf16(ah[rg], wl, acc[rg][t], 0, 0, 0);
            }
        }
    }

#pragma unroll
    for (int rg = 0; rg < 2; ++rg) {
        const int r0 = rowBase + rg * 16 + quad * 4;
        float dv[4];
#pragma unroll
        for (int r = 0; r < 4; ++r) {
            int rr = r0 + r;
            dv[r] = (rr < NN) ? dinv[rr] : 0.f;
        }
#pragma unroll
        for (int t = 0; t < NTW; ++t) {
            const int col = colPanel * (Dc / 2) + t * 16 + m;
#pragma unroll
            for (int r = 0; r < 4; ++r) {
                int rr = r0 + r;
                if (rr < NN) {
                    size_t o = ((size_t)(col >> 5) * (NN + 1) + rr) * 32 + (col & 31);
                    gs[o] = f2bf(acc[rg][t][r] * dv[r]);
                }
            }
        }
    }
}

// ---------------- sliced aggregation v3 --------------------------------------
// Block = (slice, 4-node group), slice = blockIdx & (NSL-1) -> each XCD gathers
// only its own 3.2 MB slice (L2-resident; FETCH 356->36 MB proven in r2).
// Wave per (node, slice): 8 edge-groups of 8 lanes; lane owns 8 B (uint2 = 4
// bf16 features). All pipeline state in named scalars (NO runtime-indexed
// arrays -> no cndmask chains / scratch; r2's 2x slowdown was exactly that).
// Decoupled pipeline: srcs b+4/b+5 load while rows b+2/b+3 are in flight and
// rows b/b+1 are consumed.

template <int Dc, bool FINAL>
__global__ __launch_bounds__(256) void agg_kernel(const u16* __restrict__ gs,
                                                  const int* __restrict__ rowp,
                                                  const u16* __restrict__ srcs,
                                                  const float* __restrict__ dinv,
                                                  const float* __restrict__ bias,
                                                  float* __restrict__ vs,
                                                  float* __restrict__ part,
                                                  float* __restrict__ outf) {
    constexpr int NSL = Dc / 32;
    constexpr int SH = (NSL == 8) ? 3 : 2;
    const int slice = blockIdx.x & (NSL - 1);
    const int grp = blockIdx.x >> SH;
    const int wid = threadIdx.x >> 6, lane = threadIdx.x & 63;
    const int node = grp * 4 + wid;
    const int eg = lane >> 3, cs = lane & 7;

    // uint2 view of this slice; lane's 8-byte column folded into the base.
    const uint2* gsl = (const uint2*)(gs + (size_t)slice * (NN + 1) * 32) + cs;

    float a0 = 0.f, a1 = 0.f, a2 = 0.f, a3 = 0.f;
    if (eg == 0) {   // self term, counted once
        uint2 v = gsl[(size_t)node * 8];
        a0 = ubf_lo(v.x); a1 = ubf_hi(v.x);
        a2 = ubf_lo(v.y); a3 = ubf_hi(v.y);
    }

    const int e0 = rowp[node];
    const int nb = (rowp[node + 1] - e0) >> 3;   // padded: whole batches of 8
    const u16* sp = srcs + e0 + eg;              // this lane's src slot stream

    if (nb > 0) {
        const int lastb = nb - 1;                // clamp (dup loads never consumed)
        int sA = (int)sp[0];
        int sB = (int)sp[(size_t)(0 < lastb ? 1 : lastb) * 8];
        uint2 rA = gsl[(size_t)sA * 8];
        uint2 rB = gsl[(size_t)sB * 8];
        int i2 = 2 > lastb ? lastb : 2;
        int i3 = 3 > lastb ? lastb : 3;
        int sC = (int)sp[(size_t)i2 * 8];
        int sD = (int)sp[(size_t)i3 * 8];
        int b = 0;
        for (;;) {
            uint2 rC = gsl[(size_t)sC * 8];      // rows b+2, b+3 in flight
            uint2 rD = gsl[(size_t)sD * 8];
            int i4 = b + 4 > lastb ? lastb : b + 4;
            int i5 = b + 5 > lastb ? lastb : b + 5;
            int sC2 = (int)sp[(size_t)i4 * 8];   // srcs b+4, b+5 in flight
            int sD2 = (int)sp[(size_t)i5 * 8];
            a0 += ubf_lo(rA.x); a1 += ubf_hi(rA.x);  // consume batch b
            a2 += ubf_lo(rA.y); a3 += ubf_hi(rA.y);
            if (b + 1 >= nb) break;
            a0 += ubf_lo(rB.x); a1 += ubf_hi(rB.x);  // consume batch b+1
            a2 += ubf_lo(rB.y); a3 += ubf_hi(rB.y);
            if (b + 2 >= nb) break;
            rA = rC; rB = rD; sC = sC2; sD = sD2;
            b += 2;
        }
    }

    // reduce across the 8 edge-groups (lanes with equal cs)
    a0 += __shfl_xor(a0, 8, 64);  a1 += __shfl_xor(a1, 8, 64);
    a2 += __shfl_xor(a2, 8, 64);  a3 += __shfl_xor(a3, 8, 64);
    a0 += __shfl_xor(a0, 16, 64); a1 += __shfl_xor(a1, 16, 64);
    a2 += __shfl_xor(a2, 16, 64); a3 += __shfl_xor(a3, 16, 64);
    a0 += __shfl_xor(a0, 32, 64); a1 += __shfl_xor(a1, 32, 64);
    a2 += __shfl_xor(a2, 32, 64); a3 += __shfl_xor(a3, 32, 64);

    const float dv = dinv[node];
    const int f = slice * 32 + cs * 4;
    f32x4 bb = *(const f32x4*)(bias + f);
    const float v0 = a0 * dv + bb.x;
    const float v1 = a1 * dv + bb.y;
    const float v2 = a2 * dv + bb.z;
    const float v3 = a3 * dv + bb.w;

    if (FINAL) {
        if (eg == 0)
            *(f32x4*)(outf + (size_t)node * Dc + f) = (f32x4){v0, v1, v2, v3};
    } else {
        if (eg == 0)
            *(f32x4*)(vs + ((size_t)slice * NN + node) * 32 + cs * 4) =
                (f32x4){v0, v1, v2, v3};
        float p1 = v0 + v1 + v2 + v3;
        float p2 = v0 * v0 + v1 * v1 + v2 * v2 + v3 * v3;
        p1 += __shfl_xor(p1, 1, 64); p2 += __shfl_xor(p2, 1, 64);
        p1 += __shfl_xor(p1, 2, 64); p2 += __shfl_xor(p2, 2, 64);
        p1 += __shfl_xor(p1, 4, 64); p2 += __shfl_xor(p2, 4, 64);
        if (lane == 0)
            *(f32x2*)(part + ((size_t)node * NSL + slice) * 2) = (f32x2){p1, p2};
    }
}

// ---------------- LN + SiLU + bf16 hi/lo split (streaming) -------------------
// wave per node; lane owns 4 consecutive features. Reads sliced v + partials.
__global__ __launch_bounds__(256) void ln_kernel(const float* __restrict__ vs,
                                                 const float* __restrict__ part,
                                                 const float* __restrict__ gamma,
                                                 const float* __restrict__ beta,
                                                 u16* __restrict__ xhi,
                                                 u16* __restrict__ xlo) {
    const int wid = threadIdx.x >> 6, lane = threadIdx.x & 63;
    const int node = blockIdx.x * 4 + wid;
    const int s = lane >> 3, o = (lane & 7) * 4;

    f32x4 vv = *(const f32x4*)(vs + ((size_t)s * NN + node) * 32 + o);
    f32x2 p = *(const f32x2*)(part + ((size_t)node * 8 + (lane & 7)) * 2);
    float s1 = p.x, s2 = p.y;
    s1 += __shfl_xor(s1, 1, 64); s2 += __shfl_xor(s2, 1, 64);
    s1 += __shfl_xor(s1, 2, 64); s2 += __shfl_xor(s2, 2, 64);
    s1 += __shfl_xor(s1, 4, 64); s2 += __shfl_xor(s2, 4, 64);

    const float mu = s1 * (1.f / 256.f);
    const float var = s2 * (1.f / 256.f) - mu * mu;
    const float rstd = rsqrtf(fmaxf(var, 0.f) + 1e-5f);

    const int f = s * 32 + o;
    u16 hh[4], ll[4];
#pragma unroll
    for (int j = 0; j < 4; ++j) {
        float y = (vv[j] - mu) * rstd * gamma[f + j] + beta[f + j];
        y = y / (1.f + __expf(-y));
        split2(y, hh[j], ll[j]);
    }
    uint2 oh, ol;
    oh.x = (u32)hh[0] | ((u32)hh[1] << 16);
    oh.y = (u32)hh[2] | ((u32)hh[3] << 16);
    ol.x = (u32)ll[0] | ((u32)ll[1] << 16);
    ol.y = (u32)ll[2] | ((u32)ll[3] << 16);
    *(uint2*)(xhi + (size_t)node * 256 + f) = oh;
    *(uint2*)(xlo + (size_t)node * 256 + f) = ol;
}

// ---------------- launcher ----------------

extern "C" void kernel_launch(void* const* d_in, const int* in_sizes, int n_in,
                              void* d_out, int out_size, void* d_ws, size_t ws_size,
                              hipStream_t stream) {
    (void)in_sizes; (void)n_in; (void)out_size; (void)ws_size;
    const float* x_in  = (const float*)d_in[0];
    const int*   ei    = (const int*)d_in[1];
    const float* W_in  = (const float*)d_in[2];
    const float* b_in  = (const float*)d_in[3];
    const float* W_mid = (const float*)d_in[4];
    const float* b_mid = (const float*)d_in[5];
    const float* W_out = (const float*)d_in[6];
    const float* b_out = (const float*)d_in[7];
    const float* gamma = (const float*)d_in[8];
    const float* beta  = (const float*)d_in[9];

    char* ws = (char*)d_ws;
    size_t off = 0;
    auto alloc = [&](size_t bytes) -> char* {
        char* p = ws + off;
        off += (bytes + 255) & ~(size_t)255;
        return p;
    };
    float* dinv   = (float*)alloc((size_t)NN * 4);
    int* counts   = (int*)alloc((size_t)NN * 4);
    int* cpad     = (int*)alloc((size_t)NN * 4);
    int* rowp     = (int*)alloc((size_t)(NN + 1) * 4);
    int* rank     = (int*)alloc((size_t)NE * 4);
    u16* srcs     = (u16*)alloc((size_t)PADCAP * 2);
    u16* whi_in   = (u16*)alloc((size_t)DIN * DMID * 2);
    u16* wlo_in   = (u16*)alloc((size_t)DIN * DMID * 2);
    u16* whi_mid  = (u16*)alloc((size_t)NMID * DMID * DMID * 2);
    u16* wlo_mid  = (u16*)alloc((size_t)NMID * DMID * DMID * 2);
    u16* whi_out  = (u16*)alloc((size_t)DMID * DOUT * 2);
    u16* wlo_out  = (u16*)alloc((size_t)DMID * DOUT * 2);
    u16* xhi      = (u16*)alloc((size_t)NN * DMID * 2);
    u16* xlo      = (u16*)alloc((size_t)NN * DMID * 2);
    u16* gs       = (u16*)alloc((size_t)8 * (NN + 1) * 32 * 2);  // sliced g
    float* vs     = (float*)alloc((size_t)NN * DMID * 4);        // pre-LN v, sliced
    float* part   = (float*)alloc((size_t)NN * 8 * 2 * 4);       // (sum, sumsq)

    hipMemsetAsync(counts, 0, (size_t)NN * 4, stream);

    const int EB4 = (NE / 4 + 255) / 256;       // 1563
    const int NBK = (NN + 255) / 256;           // 196
    rank_kernel<<<EB4, 256, 0, stream>>>(ei, counts, rank);
    pad_kernel<<<NBK, 256, 0, stream>>>(counts, cpad, dinv);
    scan_kernel<<<1, 1024, 0, stream>>>(cpad, rowp);
    fill16_kernel<<<(PADCAP / 8 + 255) / 256, 256, 0, stream>>>(srcs);
    scatter16_kernel<<<EB4, 256, 0, stream>>>(ei, rowp, rank, srcs);
    zsent_kernel<<<1, 256, 0, stream>>>(gs);

    wsplit_kernel<<<(DIN * DMID + 255) / 256, 256, 0, stream>>>(W_in, whi_in, wlo_in, DIN, DMID);
    for (int i = 0; i < NMID; ++i)
        wsplit_kernel<<<(DMID * DMID + 255) / 256, 256, 0, stream>>>(
            W_mid + (size_t)i * DMID * DMID, whi_mid + (size_t)i * DMID * DMID,
            wlo_mid + (size_t)i * DMID * DMID, DMID, DMID);
    wsplit_kernel<<<(DMID * DOUT + 255) / 256, 256, 0, stream>>>(W_out, whi_out, wlo_out, DMID, DOUT);
    xsplit_kernel<<<1024, 256, 0, stream>>>(x_in, xhi, xlo);

    const int GB = (NN + 127) / 128;            // 391 (8 waves/block)
    const int AGM = (NN / 4) * 8;               // 100000 blocks: 8 slices x node-groups
    const int AGF = (NN / 4) * 4;               // 50000 blocks: 4 slices
    const int LNB = NN / 4;                     // 12500

    // layer 0: 128 -> 256
    gemm_kernel<DIN, DMID><<<GB, 512, 0, stream>>>(xhi, xlo, whi_in, wlo_in, dinv, gs);
    agg_kernel<DMID, false><<<AGM, 256, 0, stream>>>(gs, rowp, srcs, dinv, b_in,
                                                     vs, part, nullptr);
    ln_kernel<<<LNB, 256, 0, stream>>>(vs, part, gamma, beta, xhi, xlo);
    // 8 mid layers: 256 -> 256
    for (int i = 0; i < NMID; ++i) {
        gemm_kernel<DMID, DMID><<<GB, 512, 0, stream>>>(xhi, xlo,
                                                        whi_mid + (size_t)i * DMID * DMID,
                                                        wlo_mid + (size_t)i * DMID * DMID,
                                                        dinv, gs);
        agg_kernel<DMID, false><<<AGM, 256, 0, stream>>>(gs, rowp, srcs, dinv,
                                                         b_mid + (size_t)i * DMID,
                                                         vs, part, nullptr);
        ln_kernel<<<LNB, 256, 0, stream>>>(vs, part,
                                           gamma + (size_t)(i + 1) * DMID,
                                           beta + (size_t)(i + 1) * DMID, xhi, xlo);
    }
    // final layer: 256 -> 128, no LN/SiLU; writes fp32 out directly
    gemm_kernel<DMID, DOUT><<<GB, 512, 0, stream>>>(xhi, xlo, whi_out, wlo_out, dinv, gs);
    agg_kernel<DOUT, true><<<AGF, 256, 0, stream>>>(gs, rowp, srcs, dinv, b_out,
                                                    nullptr, nullptr, (float*)d_out);
}

// Round 4
// 2191.105 us; speedup vs baseline: 1.2521x; 1.0561x over previous
//
#include <hip/hip_runtime.h>
#include <stdint.h>

#define NN   50000
#define NE   1600000
#define DIN  128
#define DMID 256
#define DOUT 128
#define NMID 8
#define MAXD 2048                 // degree histogram bins (true max ~75)
#define NGRP 784                  // node groups of 64 (degree-sorted)
#define NNP  (NGRP * 64)          // 50176: perm padded with sentinel NN
#define ECAP (NE + 64 * MAXD)     // transposed edge-slot capacity (proof: sorted)

#define AS1 __attribute__((address_space(1)))
#define AS3 __attribute__((address_space(3)))

typedef unsigned short u16;
typedef unsigned int   u32;
typedef __attribute__((ext_vector_type(8))) short short8;
typedef __attribute__((ext_vector_type(4))) float f32x4;
typedef __attribute__((ext_vector_type(2))) float f32x2;
typedef __attribute__((ext_vector_type(4))) int i32x4;

__device__ __forceinline__ float bf2f(u32 u) {
    union { u32 i; float f; } c; c.i = u << 16; return c.f;
}
__device__ __forceinline__ float ubf_lo(u32 v) {
    union { u32 i; float f; } c; c.i = v << 16; return c.f;
}
__device__ __forceinline__ float ubf_hi(u32 v) {
    union { u32 i; float f; } c; c.i = v & 0xffff0000u; return c.f;
}
__device__ __forceinline__ u16 f2bf(float f) {
    union { float f; u32 i; } c; c.f = f;
    u32 u = c.i;
    return (u16)((u + 0x7fffu + ((u >> 16) & 1u)) >> 16);
}
__device__ __forceinline__ void split2(float v, u16& hi, u16& lo) {
    hi = f2bf(v);
    float r = v - bf2f(hi);
    lo = f2bf(r);
}

// ---------------- preprocessing ----------------
// pass 1: per-edge rank within its dst bucket; counts[] = true degree after.
__global__ void rank_kernel(const int* __restrict__ ei, int* __restrict__ counts,
                            int* __restrict__ rank) {
    int i = (blockIdx.x * blockDim.x + threadIdx.x) * 4;
    if (i < NE) {
        i32x4 d = *(const i32x4*)(ei + NE + i);
        i32x4 r;
        r.x = atomicAdd(&counts[d.x], 1);
        r.y = atomicAdd(&counts[d.y], 1);
        r.z = atomicAdd(&counts[d.z], 1);
        r.w = atomicAdd(&counts[d.w], 1);
        *(i32x4*)(rank + i) = r;
    }
}

__global__ void dinv_kernel(const int* __restrict__ counts, float* __restrict__ dinv) {
    int i = blockIdx.x * blockDim.x + threadIdx.x;
    if (i < NN) dinv[i] = rsqrtf((float)counts[i] + 1.0f);
}

// degree histogram
__global__ void hist_kernel(const int* __restrict__ counts, int* __restrict__ hist) {
    int i = blockIdx.x * blockDim.x + threadIdx.x;
    if (i < NN) {
        int d = counts[i];
        atomicAdd(&hist[d < MAXD ? d : MAXD - 1], 1);
    }
}

// binoff[d] = #nodes with degree > d  (descending-sort start offsets)
__global__ __launch_bounds__(1024) void boff_kernel(const int* __restrict__ hist,
                                                    int* __restrict__ binoff) {
    __shared__ int sh[1024];
    const int t = threadIdx.x;
    int h0 = hist[MAXD - 1 - 2 * t];   // higher degree of the pair
    int h1 = hist[MAXD - 2 - 2 * t];
    sh[t] = h0 + h1;
    __syncthreads();
    for (int offs = 1; offs < 1024; offs <<= 1) {
        int v = (t >= offs) ? sh[t - offs] : 0;
        __syncthreads();
        sh[t] += v;
        __syncthreads();
    }
    int base = (t == 0) ? 0 : sh[t - 1];
    binoff[MAXD - 1 - 2 * t] = base;
    binoff[MAXD - 2 - 2 * t] = base + h0;
}

// counting-sort scatter: perm[pos]=node (degree-descending), posv/degp inverses.
__global__ void psort_kernel(const int* __restrict__ counts, int* __restrict__ binoff,
                             int* __restrict__ perm, int* __restrict__ posv,
                             int* __restrict__ degp) {
    int i = blockIdx.x * blockDim.x + threadIdx.x;
    if (i < NN) {
        int d = counts[i];
        int b = d < MAXD ? d : MAXD - 1;
        int pos = atomicAdd(&binoff[b], 1);
        perm[pos] = i;
        posv[i] = pos;
        degp[pos] = d;
    }
}

// pad perm tail with sentinel node NN (zero row in gs), degree 0.
__global__ void ptail_kernel(int* __restrict__ perm, int* __restrict__ degp) {
    int i = NN + threadIdx.x;
    if (i < NNP) { perm[i] = NN; degp[i] = 0; }
}

// per-group (64 nodes) max degree = transposed edge-slot rows for that group.
__global__ void gcap_kernel(const int* __restrict__ degp, int* __restrict__ gcap) {
    int g = blockIdx.x * blockDim.x + threadIdx.x;
    if (g < NGRP) {
        int m = 0;
        for (int j = 0; j < 64; ++j) {
            int d = degp[g * 64 + j];
            m = d > m ? d : m;
        }
        gcap[g] = m;
    }
}

// exclusive prefix of gcap*64 -> gbase
__global__ __launch_bounds__(1024) void gscan_kernel(const int* __restrict__ gcap,
                                                     int* __restrict__ gbase) {
    __shared__ int sh[1024];
    const int t = threadIdx.x;
    int v = (t < NGRP) ? gcap[t] * 64 : 0;
    sh[t] = v;
    __syncthreads();
    for (int offs = 1; offs < 1024; offs <<= 1) {
        int x = (t >= offs) ? sh[t - offs] : 0;
        __syncthreads();
        sh[t] += x;
        __syncthreads();
    }
    if (t < NGRP) gbase[t] = sh[t] - v;
}

// pass 2: scatter src ids into group-transposed slots: esrc[gbase[g] + r*64 + lane].
__global__ void escat_kernel(const int* __restrict__ ei, const int* __restrict__ rank,
                             const int* __restrict__ posv, const int* __restrict__ gbase,
                             u16* __restrict__ esrc) {
    int i = (blockIdx.x * blockDim.x + threadIdx.x) * 4;
    if (i < NE) {
        i32x4 d = *(const i32x4*)(ei + NE + i);
        i32x4 s = *(const i32x4*)(ei + i);
        i32x4 r = *(const i32x4*)(rank + i);
        { int p = posv[d.x]; esrc[gbase[p >> 6] + r.x * 64 + (p & 63)] = (u16)s.x; }
        { int p = posv[d.y]; esrc[gbase[p >> 6] + r.y * 64 + (p & 63)] = (u16)s.y; }
        { int p = posv[d.z]; esrc[gbase[p >> 6] + r.z * 64 + (p & 63)] = (u16)s.z; }
        { int p = posv[d.w]; esrc[gbase[p >> 6] + r.w * 64 + (p & 63)] = (u16)s.w; }
    }
}

// zero the sentinel row (node NN) of each of the 8 slices of gs.
__global__ void zsent_kernel(u16* __restrict__ gs) {
    int s = threadIdx.x >> 5, c = threadIdx.x & 31;
    gs[((size_t)s * (NN + 1) + NN) * 32 + c] = 0;
}

// W [K x Dc] fp32 row-major -> slice-major bf16 split: Whi[((k/32)*Dc + d)*32 + k%32]
__global__ void wsplit_kernel(const float* __restrict__ W, u16* __restrict__ Whi,
                              u16* __restrict__ Wlo, int K, int Dc) {
    int idx = blockIdx.x * blockDim.x + threadIdx.x;
    if (idx < K * Dc) {
        int k = idx / Dc, d = idx - k * Dc;
        u16 hi, lo;
        split2(W[idx], hi, lo);
        size_t o = ((size_t)(k >> 5) * Dc + d) * 32 + (k & 31);
        Whi[o] = hi;
        Wlo[o] = lo;
    }
}

// x [NN][128] fp32 -> row-major bf16 hi/lo
__global__ void xsplit_kernel(const float* __restrict__ x, u16* __restrict__ xhi,
                              u16* __restrict__ xlo) {
    int i = blockIdx.x * blockDim.x + threadIdx.x;
    int stride = gridDim.x * blockDim.x;
    for (; i < NN * DIN; i += stride) {
        u16 hi, lo;
        split2(x[i], hi, lo);
        xhi[i] = hi;
        xlo[i] = lo;
    }
}

// ---------------- GEMM: gs = sliced((x @ W) * dinv[row]) -------------------
// gs layout: [slice][node(+1)][32] bf16 — feature-column-blocked so the agg
// gather per slice has a 3.2 MB working set (fits one XCD's 4 MB L2).
template <int K, int Dc>
__global__ __launch_bounds__(512, 4) void gemm_kernel(const u16* __restrict__ xhi,
                                                      const u16* __restrict__ xlo,
                                                      const u16* __restrict__ whi,
                                                      const u16* __restrict__ wlo,
                                                      const float* __restrict__ dinv,
                                                      u16* __restrict__ gs) {
    constexpr int NTW = Dc / 32;
    constexpr int KS = K / 32;
    __shared__ u16 bh[Dc * 32];
    __shared__ u16 bl[Dc * 32];
    const int tid = threadIdx.x;
    const int wid = tid >> 6;
    const int rowPanel = wid >> 1;
    const int colPanel = wid & 1;
    const int lane = tid & 63;
    const int m = lane & 15, quad = lane >> 4;
    const int rowBase = blockIdx.x * 128 + rowPanel * 32;

    f32x4 acc[2][NTW];
#pragma unroll
    for (int rg = 0; rg < 2; ++rg)
#pragma unroll
        for (int t = 0; t < NTW; ++t) acc[rg][t] = (f32x4){0.f, 0.f, 0.f, 0.f};

    size_t arow[2];
#pragma unroll
    for (int rg = 0; rg < 2; ++rg) {
        int rowA = rowBase + rg * 16 + m;
        if (rowA > NN - 1) rowA = NN - 1;
        arow[rg] = (size_t)rowA * K + quad * 8;
    }

    for (int ks = 0; ks < KS; ++ks) {
        const u16* sh_src = whi + (size_t)ks * Dc * 32;
        const u16* sl_src = wlo + (size_t)ks * Dc * 32;
        __syncthreads();
#pragma unroll
        for (int i = 0; i < Dc * 4; i += 512) {
            int j = i + tid;
            __builtin_amdgcn_global_load_lds((const AS1 void*)(sh_src + j * 8),
                                             (AS3 void*)((AS3 u16*)bh + j * 8), 16, 0, 0);
            __builtin_amdgcn_global_load_lds((const AS1 void*)(sl_src + j * 8),
                                             (AS3 void*)((AS3 u16*)bl + j * 8), 16, 0, 0);
        }
        short8 ah[2], al[2];
#pragma unroll
        for (int rg = 0; rg < 2; ++rg) {
            ah[rg] = *(const short8*)(xhi + arow[rg] + ks * 32);
            al[rg] = *(const short8*)(xlo + arow[rg] + ks * 32);
        }
        __syncthreads();
#pragma unroll
        for (int t = 0; t < NTW; ++t) {
            const int bo = ((colPanel * NTW + t) * 16 + m) * 32 + quad * 8;
            short8 wh = *(const short8*)(bh + bo);
            short8 wl = *(const short8*)(bl + bo);
#pragma unroll
            for (int rg = 0; rg < 2; ++rg) {
                acc[rg][t] = __builtin_amdgcn_mfma_f32_16x16x32_bf16(ah[rg], wh, acc[rg][t], 0, 0, 0);
                acc[rg][t] = __builtin_amdgcn_mfma_f32_16x16x32_bf16(al[rg], wh, acc[rg][t], 0, 0, 0);
                acc[rg][t] = __builtin_amdgcn_mfma_f32_16x16x32_bf16(ah[rg], wl, acc[rg][t], 0, 0, 0);
            }
        }
    }

#pragma unroll
    for (int rg = 0; rg < 2; ++rg) {
        const int r0 = rowBase + rg * 16 + quad * 4;
        float dv[4];
#pragma unroll
        for (int r = 0; r < 4; ++r) {
            int rr = r0 + r;
            dv[r] = (rr < NN) ? dinv[rr] : 0.f;
        }
#pragma unroll
        for (int t = 0; t < NTW; ++t) {
            const int col = colPanel * (Dc / 2) + t * 16 + m;
#pragma unroll
            for (int r = 0; r < 4; ++r) {
                int rr = r0 + r;
                if (rr < NN) {
                    size_t o = ((size_t)(col >> 5) * (NN + 1) + rr) * 32 + (col & 31);
                    gs[o] = f2bf(acc[rg][t][r] * dv[r]);
                }
            }
        }
    }
}

// ---------------- sliced aggregation v4: lane-per-node -----------------------
// Block = (slice, 4 degree-sorted 64-node groups), slice = blockIdx & (NSL-1)
// -> each XCD gathers only its own 3.2 MB slice (L2-resident; proven r2/r3).
// ONE LANE owns one (node, slice): 32 f32 accumulators, serial edge walk,
// 64 B row per edge via 4 x dwordx4. No shfl reductions, no CSR replication
// across lanes. Degree sort keeps lanes converged; transposed esrc slots
// (gbase[g] + e*64 + lane) make src-id loads coalesced. 1-deep row prefetch.

__device__ __forceinline__ void acc_row(float (&a)[32], uint4 R0, uint4 R1,
                                        uint4 R2, uint4 R3) {
#define ACC2(i, w) a[i] += ubf_lo(w); a[i + 1] += ubf_hi(w)
    ACC2(0, R0.x);  ACC2(2, R0.y);  ACC2(4, R0.z);  ACC2(6, R0.w);
    ACC2(8, R1.x);  ACC2(10, R1.y); ACC2(12, R1.z); ACC2(14, R1.w);
    ACC2(16, R2.x); ACC2(18, R2.y); ACC2(20, R2.z); ACC2(22, R2.w);
    ACC2(24, R3.x); ACC2(26, R3.y); ACC2(28, R3.z); ACC2(30, R3.w);
#undef ACC2
}

template <int Dc, bool FINAL>
__global__ __launch_bounds__(256, 4) void agg_kernel(const u16* __restrict__ gs,
                                                     const u16* __restrict__ esrc,
                                                     const int* __restrict__ gbase,
                                                     const int* __restrict__ perm,
                                                     const int* __restrict__ degp,
                                                     const float* __restrict__ dinv,
                                                     const float* __restrict__ bias,
                                                     float* __restrict__ vs,
                                                     float* __restrict__ part,
                                                     float* __restrict__ outf) {
    constexpr int NSL = Dc / 32;
    constexpr int SH = (NSL == 8) ? 3 : 2;
    const int slice = blockIdx.x & (NSL - 1);
    const int grp4 = blockIdx.x >> SH;
    const int wid = threadIdx.x >> 6, lane = threadIdx.x & 63;
    const int grp = grp4 * 4 + wid;          // 0..NGRP-1
    const int gpos = grp * 64 + lane;        // perm index
    const int node = perm[gpos];             // NN for padding lanes
    const int deg = degp[gpos];

    const u16* gslb = gs + (size_t)slice * (NN + 1) * 32;
    const u16* ep = esrc + gbase[grp] + lane;

    float a[32];
#pragma unroll
    for (int j = 0; j < 32; ++j) a[j] = 0.f;

    // self row first (sentinel node NN reads the zero row)
    const uint4* rp0 = (const uint4*)(gslb + (size_t)node * 32);
    uint4 A0 = rp0[0], A1 = rp0[1], A2 = rp0[2], A3 = rp0[3];
    int sNxt = (deg > 0) ? (int)ep[0] : node;
    int t = 0;
    for (;;) {
        const uint4* rq = (const uint4*)(gslb + (size_t)sNxt * 32);
        uint4 B0 = rq[0], B1 = rq[1], B2 = rq[2], B3 = rq[3];   // next row in flight
        int sN2 = (t + 1 < deg) ? (int)ep[(t + 1) * 64] : sNxt; // next src in flight
        acc_row(a, A0, A1, A2, A3);                             // consume current
        ++t;
        if (t > deg) break;                                     // consumed self + deg
        A0 = B0; A1 = B1; A2 = B2; A3 = B3;
        sNxt = sN2;
    }

    if (node < NN) {
        const float dv = dinv[node];
        float v[32];
#pragma unroll
        for (int j = 0; j < 32; ++j) v[j] = a[j] * dv + bias[slice * 32 + j];

        if (FINAL) {
            float* op = outf + (size_t)node * Dc + slice * 32;
#pragma unroll
            for (int q = 0; q < 8; ++q)
                *(f32x4*)(op + q * 4) = (f32x4){v[q * 4], v[q * 4 + 1],
                                                v[q * 4 + 2], v[q * 4 + 3]};
        } else {
            float* vp = vs + ((size_t)slice * NN + node) * 32;
            float p1 = 0.f, p2 = 0.f;
#pragma unroll
            for (int q = 0; q < 8; ++q)
                *(f32x4*)(vp + q * 4) = (f32x4){v[q * 4], v[q * 4 + 1],
                                                v[q * 4 + 2], v[q * 4 + 3]};
#pragma unroll
            for (int j = 0; j < 32; ++j) {
                p1 += v[j];
                p2 += v[j] * v[j];
            }
            // part[slice][node]: per-XCD-contiguous -> no cross-XCD false sharing
            *(f32x2*)(part + ((size_t)slice * NN + node) * 2) = (f32x2){p1, p2};
        }
    }
}

// ---------------- LN + SiLU + bf16 hi/lo split (streaming) -------------------
// wave per node; lane owns 4 consecutive features. Reads sliced v + partials.
__global__ __launch_bounds__(256) void ln_kernel(const float* __restrict__ vs,
                                                 const float* __restrict__ part,
                                                 const float* __restrict__ gamma,
                                                 const float* __restrict__ beta,
                                                 u16* __restrict__ xhi,
                                                 u16* __restrict__ xlo) {
    const int wid = threadIdx.x >> 6, lane = threadIdx.x & 63;
    const int node = blockIdx.x * 4 + wid;
    const int s = lane >> 3, o = (lane & 7) * 4;

    f32x4 vv = *(const f32x4*)(vs + ((size_t)s * NN + node) * 32 + o);
    f32x2 p = *(const f32x2*)(part + ((size_t)(lane & 7) * NN + node) * 2);
    float s1 = p.x, s2 = p.y;
    s1 += __shfl_xor(s1, 1, 64); s2 += __shfl_xor(s2, 1, 64);
    s1 += __shfl_xor(s1, 2, 64); s2 += __shfl_xor(s2, 2, 64);
    s1 += __shfl_xor(s1, 4, 64); s2 += __shfl_xor(s2, 4, 64);

    const float mu = s1 * (1.f / 256.f);
    const float var = s2 * (1.f / 256.f) - mu * mu;
    const float rstd = rsqrtf(fmaxf(var, 0.f) + 1e-5f);

    const int f = s * 32 + o;
    u16 hh[4], ll[4];
#pragma unroll
    for (int j = 0; j < 4; ++j) {
        float y = (vv[j] - mu) * rstd * gamma[f + j] + beta[f + j];
        y = y / (1.f + __expf(-y));
        split2(y, hh[j], ll[j]);
    }
    uint2 oh, ol;
    oh.x = (u32)hh[0] | ((u32)hh[1] << 16);
    oh.y = (u32)hh[2] | ((u32)hh[3] << 16);
    ol.x = (u32)ll[0] | ((u32)ll[1] << 16);
    ol.y = (u32)ll[2] | ((u32)ll[3] << 16);
    *(uint2*)(xhi + (size_t)node * 256 + f) = oh;
    *(uint2*)(xlo + (size_t)node * 256 + f) = ol;
}

// ---------------- launcher ----------------

extern "C" void kernel_launch(void* const* d_in, const int* in_sizes, int n_in,
                              void* d_out, int out_size, void* d_ws, size_t ws_size,
                              hipStream_t stream) {
    (void)in_sizes; (void)n_in; (void)out_size; (void)ws_size;
    const float* x_in  = (const float*)d_in[0];
    const int*   ei    = (const int*)d_in[1];
    const float* W_in  = (const float*)d_in[2];
    const float* b_in  = (const float*)d_in[3];
    const float* W_mid = (const float*)d_in[4];
    const float* b_mid = (const float*)d_in[5];
    const float* W_out = (const float*)d_in[6];
    const float* b_out = (const float*)d_in[7];
    const float* gamma = (const float*)d_in[8];
    const float* beta  = (const float*)d_in[9];

    char* ws = (char*)d_ws;
    size_t off = 0;
    auto alloc = [&](size_t bytes) -> char* {
        char* p = ws + off;
        off += (bytes + 255) & ~(size_t)255;
        return p;
    };
    float* dinv   = (float*)alloc((size_t)NN * 4);
    int* counts   = (int*)alloc((size_t)NN * 4);
    int* rank     = (int*)alloc((size_t)NE * 4);
    int* hist     = (int*)alloc((size_t)MAXD * 4);
    int* binoff   = (int*)alloc((size_t)MAXD * 4);
    int* perm     = (int*)alloc((size_t)NNP * 4);
    int* posv     = (int*)alloc((size_t)NN * 4);
    int* degp     = (int*)alloc((size_t)NNP * 4);
    int* gcap     = (int*)alloc((size_t)NGRP * 4);
    int* gbase    = (int*)alloc((size_t)NGRP * 4);
    u16* esrc     = (u16*)alloc((size_t)ECAP * 2);
    u16* whi_in   = (u16*)alloc((size_t)DIN * DMID * 2);
    u16* wlo_in   = (u16*)alloc((size_t)DIN * DMID * 2);
    u16* whi_mid  = (u16*)alloc((size_t)NMID * DMID * DMID * 2);
    u16* wlo_mid  = (u16*)alloc((size_t)NMID * DMID * DMID * 2);
    u16* whi_out  = (u16*)alloc((size_t)DMID * DOUT * 2);
    u16* wlo_out  = (u16*)alloc((size_t)DMID * DOUT * 2);
    u16* xhi      = (u16*)alloc((size_t)NN * DMID * 2);
    u16* xlo      = (u16*)alloc((size_t)NN * DMID * 2);
    u16* gs       = (u16*)alloc((size_t)8 * (NN + 1) * 32 * 2);  // sliced g
    float* vs     = (float*)alloc((size_t)NN * DMID * 4);        // pre-LN v, sliced
    float* part   = (float*)alloc((size_t)8 * NN * 2 * 4);       // [slice][node]{2}

    hipMemsetAsync(counts, 0, (size_t)NN * 4, stream);
    hipMemsetAsync(hist, 0, (size_t)MAXD * 4, stream);

    const int EB4 = (NE / 4 + 255) / 256;       // 1563
    const int NBK = (NN + 255) / 256;           // 196
    rank_kernel<<<EB4, 256, 0, stream>>>(ei, counts, rank);
    dinv_kernel<<<NBK, 256, 0, stream>>>(counts, dinv);
    hist_kernel<<<NBK, 256, 0, stream>>>(counts, hist);
    boff_kernel<<<1, 1024, 0, stream>>>(hist, binoff);
    psort_kernel<<<NBK, 256, 0, stream>>>(counts, binoff, perm, posv, degp);
    ptail_kernel<<<1, 256, 0, stream>>>(perm, degp);
    gcap_kernel<<<(NGRP + 255) / 256, 256, 0, stream>>>(degp, gcap);
    gscan_kernel<<<1, 1024, 0, stream>>>(gcap, gbase);
    escat_kernel<<<EB4, 256, 0, stream>>>(ei, rank, posv, gbase, esrc);
    zsent_kernel<<<1, 256, 0, stream>>>(gs);

    wsplit_kernel<<<(DIN * DMID + 255) / 256, 256, 0, stream>>>(W_in, whi_in, wlo_in, DIN, DMID);
    for (int i = 0; i < NMID; ++i)
        wsplit_kernel<<<(DMID * DMID + 255) / 256, 256, 0, stream>>>(
            W_mid + (size_t)i * DMID * DMID, whi_mid + (size_t)i * DMID * DMID,
            wlo_mid + (size_t)i * DMID * DMID, DMID, DMID);
    wsplit_kernel<<<(DMID * DOUT + 255) / 256, 256, 0, stream>>>(W_out, whi_out, wlo_out, DMID, DOUT);
    xsplit_kernel<<<1024, 256, 0, stream>>>(x_in, xhi, xlo);

    const int GB = (NN + 127) / 128;            // 391 (8 waves/block)
    const int AGM = (NGRP / 4) * 8;             // 1568: 8 slices x 196 group-quads
    const int AGF = (NGRP / 4) * 4;             // 784: 4 slices
    const int LNB = NN / 4;                     // 12500

    // layer 0: 128 -> 256
    gemm_kernel<DIN, DMID><<<GB, 512, 0, stream>>>(xhi, xlo, whi_in, wlo_in, dinv, gs);
    agg_kernel<DMID, false><<<AGM, 256, 0, stream>>>(gs, esrc, gbase, perm, degp,
                                                     dinv, b_in, vs, part, nullptr);
    ln_kernel<<<LNB, 256, 0, stream>>>(vs, part, gamma, beta, xhi, xlo);
    // 8 mid layers: 256 -> 256
    for (int i = 0; i < NMID; ++i) {
        gemm_kernel<DMID, DMID><<<GB, 512, 0, stream>>>(xhi, xlo,
                                                        whi_mid + (size_t)i * DMID * DMID,
                                                        wlo_mid + (size_t)i * DMID * DMID,
                                                        dinv, gs);
        agg_kernel<DMID, false><<<AGM, 256, 0, stream>>>(gs, esrc, gbase, perm, degp,
                                                         dinv, b_mid + (size_t)i * DMID,
                                                         vs, part, nullptr);
        ln_kernel<<<LNB, 256, 0, stream>>>(vs, part,
                                           gamma + (size_t)(i + 1) * DMID,
                                           beta + (size_t)(i + 1) * DMID, xhi, xlo);
    }
    // final layer: 256 -> 128, no LN/SiLU; writes fp32 out directly
    gemm_kernel<DMID, DOUT><<<GB, 512, 0, stream>>>(xhi, xlo, whi_out, wlo_out, dinv, gs);
    agg_kernel<DOUT, true><<<AGF, 256, 0, stream>>>(gs, esrc, gbase, perm, degp,
                                                    dinv, b_out, nullptr, nullptr,
                                                    (float*)d_out);
}

// Round 5
// 1656.289 us; speedup vs baseline: 1.6565x; 1.3229x over previous
//
#include <hip/hip_runtime.h>
#include <stdint.h>

#define NN   50000
#define NE   1600000
#define DIN  128
#define DMID 256
#define DOUT 128
#define NMID 8
#define MAXD 2048                 // degree histogram bins (true max ~75)
#define NG16 3128                 // 16-node groups (3125 real + 3 pad), %4==0
#define NNP  (NG16 * 16)          // 50048: perm padded with sentinel NN
#define ECAP (NE + 64 * MAXD)     // transposed edge-slot capacity (sorted bound)

#define AS1 __attribute__((address_space(1)))
#define AS3 __attribute__((address_space(3)))

typedef unsigned short u16;
typedef unsigned int   u32;
typedef __attribute__((ext_vector_type(8))) short short8;
typedef __attribute__((ext_vector_type(4))) float f32x4;
typedef __attribute__((ext_vector_type(2))) float f32x2;
typedef __attribute__((ext_vector_type(4))) int i32x4;

__device__ __forceinline__ float bf2f(u32 u) {
    union { u32 i; float f; } c; c.i = u << 16; return c.f;
}
__device__ __forceinline__ float ubf_lo(u32 v) {
    union { u32 i; float f; } c; c.i = v << 16; return c.f;
}
__device__ __forceinline__ float ubf_hi(u32 v) {
    union { u32 i; float f; } c; c.i = v & 0xffff0000u; return c.f;
}
__device__ __forceinline__ u16 f2bf(float f) {
    union { float f; u32 i; } c; c.f = f;
    u32 u = c.i;
    return (u16)((u + 0x7fffu + ((u >> 16) & 1u)) >> 16);
}
__device__ __forceinline__ void split2(float v, u16& hi, u16& lo) {
    hi = f2bf(v);
    float r = v - bf2f(hi);
    lo = f2bf(r);
}

// ---------------- preprocessing ----------------
// pass 1: per-edge rank within its dst bucket; counts[] = true degree after.
__global__ void rank_kernel(const int* __restrict__ ei, int* __restrict__ counts,
                            int* __restrict__ rank) {
    int i = (blockIdx.x * blockDim.x + threadIdx.x) * 4;
    if (i < NE) {
        i32x4 d = *(const i32x4*)(ei + NE + i);
        i32x4 r;
        r.x = atomicAdd(&counts[d.x], 1);
        r.y = atomicAdd(&counts[d.y], 1);
        r.z = atomicAdd(&counts[d.z], 1);
        r.w = atomicAdd(&counts[d.w], 1);
        *(i32x4*)(rank + i) = r;
    }
}

__global__ void dinv_kernel(const int* __restrict__ counts, float* __restrict__ dinv) {
    int i = blockIdx.x * blockDim.x + threadIdx.x;
    if (i < NN) dinv[i] = rsqrtf((float)counts[i] + 1.0f);
}

// degree histogram
__global__ void hist_kernel(const int* __restrict__ counts, int* __restrict__ hist) {
    int i = blockIdx.x * blockDim.x + threadIdx.x;
    if (i < NN) {
        int d = counts[i];
        atomicAdd(&hist[d < MAXD ? d : MAXD - 1], 1);
    }
}

// binoff[d] = #nodes with degree > d  (descending-sort start offsets)
__global__ __launch_bounds__(1024) void boff_kernel(const int* __restrict__ hist,
                                                    int* __restrict__ binoff) {
    __shared__ int sh[1024];
    const int t = threadIdx.x;
    int h0 = hist[MAXD - 1 - 2 * t];   // higher degree of the pair
    int h1 = hist[MAXD - 2 - 2 * t];
    sh[t] = h0 + h1;
    __syncthreads();
    for (int offs = 1; offs < 1024; offs <<= 1) {
        int v = (t >= offs) ? sh[t - offs] : 0;
        __syncthreads();
        sh[t] += v;
        __syncthreads();
    }
    int base = (t == 0) ? 0 : sh[t - 1];
    binoff[MAXD - 1 - 2 * t] = base;
    binoff[MAXD - 2 - 2 * t] = base + h0;
}

// counting-sort scatter: perm[pos]=node (degree-descending), posv/degp inverses.
__global__ void psort_kernel(const int* __restrict__ counts, int* __restrict__ binoff,
                             int* __restrict__ perm, int* __restrict__ posv,
                             int* __restrict__ degp) {
    int i = blockIdx.x * blockDim.x + threadIdx.x;
    if (i < NN) {
        int d = counts[i];
        int b = d < MAXD ? d : MAXD - 1;
        int pos = atomicAdd(&binoff[b], 1);
        perm[pos] = i;
        posv[i] = pos;
        degp[pos] = d;
    }
}

// pad perm tail with sentinel node NN (zero row in gs), degree 0.
__global__ void ptail_kernel(int* __restrict__ perm, int* __restrict__ degp) {
    int i = NN + threadIdx.x;
    if (i < NNP) { perm[i] = NN; degp[i] = 0; }
}

// per-group (16 nodes) max degree = transposed edge-slot rows for that group.
__global__ void gcap_kernel(const int* __restrict__ degp, int* __restrict__ gcap) {
    int g = blockIdx.x * blockDim.x + threadIdx.x;
    if (g < NG16) {
        int m = 0;
        for (int j = 0; j < 16; ++j) {
            int d = degp[g * 16 + j];
            m = d > m ? d : m;
        }
        gcap[g] = m;
    }
}

// exclusive prefix of gcap*16 -> gbase (u16-slot units)
__global__ __launch_bounds__(1024) void gscan_kernel(const int* __restrict__ gcap,
                                                     int* __restrict__ gbase) {
    __shared__ int sh[1024];
    const int t = threadIdx.x;
    int loc[4];
    int s = 0;
#pragma unroll
    for (int j = 0; j < 4; ++j) {
        int idx = t * 4 + j;
        int v = (idx < NG16) ? gcap[idx] * 16 : 0;
        loc[j] = s;
        s += v;
    }
    sh[t] = s;
    __syncthreads();
    for (int offs = 1; offs < 1024; offs <<= 1) {
        int x = (t >= offs) ? sh[t - offs] : 0;
        __syncthreads();
        sh[t] += x;
        __syncthreads();
    }
    int base = (t == 0) ? 0 : sh[t - 1];
#pragma unroll
    for (int j = 0; j < 4; ++j) {
        int idx = t * 4 + j;
        if (idx < NG16) gbase[idx] = base + loc[j];
    }
}

// pass 2: scatter src ids into group-transposed slots: esrc[gbase[g] + r*16 + slot].
__global__ void escat_kernel(const int* __restrict__ ei, const int* __restrict__ rank,
                             const int* __restrict__ posv, const int* __restrict__ gbase,
                             u16* __restrict__ esrc) {
    int i = (blockIdx.x * blockDim.x + threadIdx.x) * 4;
    if (i < NE) {
        i32x4 d = *(const i32x4*)(ei + NE + i);
        i32x4 s = *(const i32x4*)(ei + i);
        i32x4 r = *(const i32x4*)(rank + i);
        { int p = posv[d.x]; esrc[gbase[p >> 4] + r.x * 16 + (p & 15)] = (u16)s.x; }
        { int p = posv[d.y]; esrc[gbase[p >> 4] + r.y * 16 + (p & 15)] = (u16)s.y; }
        { int p = posv[d.z]; esrc[gbase[p >> 4] + r.z * 16 + (p & 15)] = (u16)s.z; }
        { int p = posv[d.w]; esrc[gbase[p >> 4] + r.w * 16 + (p & 15)] = (u16)s.w; }
    }
}

// zero the sentinel row (node NN) of each of the 8 slices of gs.
__global__ void zsent_kernel(u16* __restrict__ gs) {
    int s = threadIdx.x >> 5, c = threadIdx.x & 31;
    gs[((size_t)s * (NN + 1) + NN) * 32 + c] = 0;
}

// W [K x Dc] fp32 row-major -> slice-major bf16 split: Whi[((k/32)*Dc + d)*32 + k%32]
__global__ void wsplit_kernel(const float* __restrict__ W, u16* __restrict__ Whi,
                              u16* __restrict__ Wlo, int K, int Dc) {
    int idx = blockIdx.x * blockDim.x + threadIdx.x;
    if (idx < K * Dc) {
        int k = idx / Dc, d = idx - k * Dc;
        u16 hi, lo;
        split2(W[idx], hi, lo);
        size_t o = ((size_t)(k >> 5) * Dc + d) * 32 + (k & 31);
        Whi[o] = hi;
        Wlo[o] = lo;
    }
}

// x [NN][128] fp32 -> row-major bf16 hi/lo
__global__ void xsplit_kernel(const float* __restrict__ x, u16* __restrict__ xhi,
                              u16* __restrict__ xlo) {
    int i = blockIdx.x * blockDim.x + threadIdx.x;
    int stride = gridDim.x * blockDim.x;
    for (; i < NN * DIN; i += stride) {
        u16 hi, lo;
        split2(x[i], hi, lo);
        xhi[i] = hi;
        xlo[i] = lo;
    }
}

// ---------------- GEMM: gs = sliced((x @ W) * dinv[row]) -------------------
// gs layout: [slice][node(+1)][32] bf16 — feature-column-blocked so the agg
// gather per slice has a 3.2 MB working set (fits one XCD's 4 MB L2).
template <int K, int Dc>
__global__ __launch_bounds__(512, 4) void gemm_kernel(const u16* __restrict__ xhi,
                                                      const u16* __restrict__ xlo,
                                                      const u16* __restrict__ whi,
                                                      const u16* __restrict__ wlo,
                                                      const float* __restrict__ dinv,
                                                      u16* __restrict__ gs) {
    constexpr int NTW = Dc / 32;
    constexpr int KS = K / 32;
    __shared__ u16 bh[Dc * 32];
    __shared__ u16 bl[Dc * 32];
    const int tid = threadIdx.x;
    const int wid = tid >> 6;
    const int rowPanel = wid >> 1;
    const int colPanel = wid & 1;
    const int lane = tid & 63;
    const int m = lane & 15, quad = lane >> 4;
    const int rowBase = blockIdx.x * 128 + rowPanel * 32;

    f32x4 acc[2][NTW];
#pragma unroll
    for (int rg = 0; rg < 2; ++rg)
#pragma unroll
        for (int t = 0; t < NTW; ++t) acc[rg][t] = (f32x4){0.f, 0.f, 0.f, 0.f};

    size_t arow[2];
#pragma unroll
    for (int rg = 0; rg < 2; ++rg) {
        int rowA = rowBase + rg * 16 + m;
        if (rowA > NN - 1) rowA = NN - 1;
        arow[rg] = (size_t)rowA * K + quad * 8;
    }

    for (int ks = 0; ks < KS; ++ks) {
        const u16* sh_src = whi + (size_t)ks * Dc * 32;
        const u16* sl_src = wlo + (size_t)ks * Dc * 32;
        __syncthreads();
#pragma unroll
        for (int i = 0; i < Dc * 4; i += 512) {
            int j = i + tid;
            __builtin_amdgcn_global_load_lds((const AS1 void*)(sh_src + j * 8),
                                             (AS3 void*)((AS3 u16*)bh + j * 8), 16, 0, 0);
            __builtin_amdgcn_global_load_lds((const AS1 void*)(sl_src + j * 8),
                                             (AS3 void*)((AS3 u16*)bl + j * 8), 16, 0, 0);
        }
        short8 ah[2], al[2];
#pragma unroll
        for (int rg = 0; rg < 2; ++rg) {
            ah[rg] = *(const short8*)(xhi + arow[rg] + ks * 32);
            al[rg] = *(const short8*)(xlo + arow[rg] + ks * 32);
        }
        __syncthreads();
#pragma unroll
        for (int t = 0; t < NTW; ++t) {
            const int bo = ((colPanel * NTW + t) * 16 + m) * 32 + quad * 8;
            short8 wh = *(const short8*)(bh + bo);
            short8 wl = *(const short8*)(bl + bo);
#pragma unroll
            for (int rg = 0; rg < 2; ++rg) {
                acc[rg][t] = __builtin_amdgcn_mfma_f32_16x16x32_bf16(ah[rg], wh, acc[rg][t], 0, 0, 0);
                acc[rg][t] = __builtin_amdgcn_mfma_f32_16x16x32_bf16(al[rg], wh, acc[rg][t], 0, 0, 0);
                acc[rg][t] = __builtin_amdgcn_mfma_f32_16x16x32_bf16(ah[rg], wl, acc[rg][t], 0, 0, 0);
            }
        }
    }

#pragma unroll
    for (int rg = 0; rg < 2; ++rg) {
        const int r0 = rowBase + rg * 16 + quad * 4;
        float dv[4];
#pragma unroll
        for (int r = 0; r < 4; ++r) {
            int rr = r0 + r;
            dv[r] = (rr < NN) ? dinv[rr] : 0.f;
        }
#pragma unroll
        for (int t = 0; t < NTW; ++t) {
            const int col = colPanel * (Dc / 2) + t * 16 + m;
#pragma unroll
            for (int r = 0; r < 4; ++r) {
                int rr = r0 + r;
                if (rr < NN) {
                    size_t o = ((size_t)(col >> 5) * (NN + 1) + rr) * 32 + (col & 31);
                    gs[o] = f2bf(acc[rg][t][r] * dv[r]);
                }
            }
        }
    }
}

// ---------------- sliced aggregation v5: quad-cooperative rows ---------------
// Block = (slice, 4 degree-sorted 16-node groups), slice = blockIdx & (NSL-1)
// -> each XCD gathers only its own 3.2 MB slice (L2-resident; proven r2-r4).
// Wave = 16 node-slots x 4 quarters: the 4 lanes of a quad read the 4
// consecutive 16B quarters of the SAME row -> intra-instruction same-line
// coalescing: 1 cache-line request per row instead of 4 (r4 was TA-request
// bound: VALU 16%, HBM 10%, 84% stall). Lane owns 8 features; LN partials
// need only a 2-shfl quad reduction. 1-deep row prefetch, 2-deep src.

template <int Dc, bool FINAL>
__global__ __launch_bounds__(256, 8) void agg_kernel(const u16* __restrict__ gs,
                                                     const u16* __restrict__ esrc,
                                                     const int* __restrict__ gbase,
                                                     const int* __restrict__ perm,
                                                     const int* __restrict__ degp,
                                                     const float* __restrict__ dinv,
                                                     const float* __restrict__ bias,
                                                     float* __restrict__ vs,
                                                     float* __restrict__ part,
                                                     float* __restrict__ outf) {
    constexpr int NSL = Dc / 32;
    constexpr int SH = (NSL == 8) ? 3 : 2;
    const int slice = blockIdx.x & (NSL - 1);
    const int grp4 = blockIdx.x >> SH;
    const int wid = threadIdx.x >> 6, lane = threadIdx.x & 63;
    const int grp = grp4 * 4 + wid;          // 16-node group id
    const int nslot = lane >> 2, q = lane & 3;
    const int gpos = grp * 16 + nslot;       // perm index
    const int node = perm[gpos];             // NN for padding lanes
    const int deg = degp[gpos];

    const u16* gslb = gs + (size_t)slice * (NN + 1) * 32 + q * 8;  // quarter base
    const u16* ep = esrc + gbase[grp] + nslot;

    float a[8];
#pragma unroll
    for (int j = 0; j < 8; ++j) a[j] = 0.f;

    // self row first (sentinel node NN reads the zero row)
    uint4 A = *(const uint4*)(gslb + (size_t)node * 32);
    int sNxt = (deg > 0) ? (int)ep[0] : node;
    int t = 0;
    for (;;) {
        uint4 B = *(const uint4*)(gslb + (size_t)sNxt * 32);        // next row in flight
        int sN2 = (t + 1 < deg) ? (int)ep[(t + 1) * 16] : sNxt;     // next src in flight
        a[0] += ubf_lo(A.x); a[1] += ubf_hi(A.x);                   // consume current
        a[2] += ubf_lo(A.y); a[3] += ubf_hi(A.y);
        a[4] += ubf_lo(A.z); a[5] += ubf_hi(A.z);
        a[6] += ubf_lo(A.w); a[7] += ubf_hi(A.w);
        ++t;
        if (t > deg) break;                                         // self + deg rows
        A = B;
        sNxt = sN2;
    }

    if (node < NN) {
        const float dv = dinv[node];
        const int f = slice * 32 + q * 8;
        float v[8];
        f32x4 b0 = *(const f32x4*)(bias + f);
        f32x4 b1 = *(const f32x4*)(bias + f + 4);
#pragma unroll
        for (int j = 0; j < 4; ++j) v[j] = a[j] * dv + b0[j];
#pragma unroll
        for (int j = 0; j < 4; ++j) v[j + 4] = a[j + 4] * dv + b1[j];

        if (FINAL) {
            float* op = outf + (size_t)node * Dc + f;
            *(f32x4*)op = (f32x4){v[0], v[1], v[2], v[3]};
            *(f32x4*)(op + 4) = (f32x4){v[4], v[5], v[6], v[7]};
        } else {
            float* vp = vs + ((size_t)slice * NN + node) * 32 + q * 8;
            *(f32x4*)vp = (f32x4){v[0], v[1], v[2], v[3]};
            *(f32x4*)(vp + 4) = (f32x4){v[4], v[5], v[6], v[7]};
            float p1 = 0.f, p2 = 0.f;
#pragma unroll
            for (int j = 0; j < 8; ++j) {
                p1 += v[j];
                p2 += v[j] * v[j];
            }
            // quad reduction (4 lanes of this node)
            p1 += __shfl_xor(p1, 1, 64); p2 += __shfl_xor(p2, 1, 64);
            p1 += __shfl_xor(p1, 2, 64); p2 += __shfl_xor(p2, 2, 64);
            // part[slice][node]: per-XCD-contiguous -> no cross-XCD false sharing
            if (q == 0)
                *(f32x2*)(part + ((size_t)slice * NN + node) * 2) = (f32x2){p1, p2};
        }
    }
}

// ---------------- LN + SiLU + bf16 hi/lo split (streaming) -------------------
// wave per node; lane owns 4 consecutive features. Reads sliced v + partials.
__global__ __launch_bounds__(256) void ln_kernel(const float* __restrict__ vs,
                                                 const float* __restrict__ part,
                                                 const float* __restrict__ gamma,
                                                 const float* __restrict__ beta,
                                                 u16* __restrict__ xhi,
                                                 u16* __restrict__ xlo) {
    const int wid = threadIdx.x >> 6, lane = threadIdx.x & 63;
    const int node = blockIdx.x * 4 + wid;
    const int s = lane >> 3, o = (lane & 7) * 4;

    f32x4 vv = *(const f32x4*)(vs + ((size_t)s * NN + node) * 32 + o);
    f32x2 p = *(const f32x2*)(part + ((size_t)(lane & 7) * NN + node) * 2);
    float s1 = p.x, s2 = p.y;
    s1 += __shfl_xor(s1, 1, 64); s2 += __shfl_xor(s2, 1, 64);
    s1 += __shfl_xor(s1, 2, 64); s2 += __shfl_xor(s2, 2, 64);
    s1 += __shfl_xor(s1, 4, 64); s2 += __shfl_xor(s2, 4, 64);

    const float mu = s1 * (1.f / 256.f);
    const float var = s2 * (1.f / 256.f) - mu * mu;
    const float rstd = rsqrtf(fmaxf(var, 0.f) + 1e-5f);

    const int f = s * 32 + o;
    u16 hh[4], ll[4];
#pragma unroll
    for (int j = 0; j < 4; ++j) {
        float y = (vv[j] - mu) * rstd * gamma[f + j] + beta[f + j];
        y = y / (1.f + __expf(-y));
        split2(y, hh[j], ll[j]);
    }
    uint2 oh, ol;
    oh.x = (u32)hh[0] | ((u32)hh[1] << 16);
    oh.y = (u32)hh[2] | ((u32)hh[3] << 16);
    ol.x = (u32)ll[0] | ((u32)ll[1] << 16);
    ol.y = (u32)ll[2] | ((u32)ll[3] << 16);
    *(uint2*)(xhi + (size_t)node * 256 + f) = oh;
    *(uint2*)(xlo + (size_t)node * 256 + f) = ol;
}

// ---------------- launcher ----------------

extern "C" void kernel_launch(void* const* d_in, const int* in_sizes, int n_in,
                              void* d_out, int out_size, void* d_ws, size_t ws_size,
                              hipStream_t stream) {
    (void)in_sizes; (void)n_in; (void)out_size; (void)ws_size;
    const float* x_in  = (const float*)d_in[0];
    const int*   ei    = (const int*)d_in[1];
    const float* W_in  = (const float*)d_in[2];
    const float* b_in  = (const float*)d_in[3];
    const float* W_mid = (const float*)d_in[4];
    const float* b_mid = (const float*)d_in[5];
    const float* W_out = (const float*)d_in[6];
    const float* b_out = (const float*)d_in[7];
    const float* gamma = (const float*)d_in[8];
    const float* beta  = (const float*)d_in[9];

    char* ws = (char*)d_ws;
    size_t off = 0;
    auto alloc = [&](size_t bytes) -> char* {
        char* p = ws + off;
        off += (bytes + 255) & ~(size_t)255;
        return p;
    };
    float* dinv   = (float*)alloc((size_t)NN * 4);
    int* counts   = (int*)alloc((size_t)NN * 4);
    int* rank     = (int*)alloc((size_t)NE * 4);
    int* hist     = (int*)alloc((size_t)MAXD * 4);
    int* binoff   = (int*)alloc((size_t)MAXD * 4);
    int* perm     = (int*)alloc((size_t)NNP * 4);
    int* posv     = (int*)alloc((size_t)NN * 4);
    int* degp     = (int*)alloc((size_t)NNP * 4);
    int* gcap     = (int*)alloc((size_t)NG16 * 4);
    int* gbase    = (int*)alloc((size_t)NG16 * 4);
    u16* esrc     = (u16*)alloc((size_t)ECAP * 2);
    u16* whi_in   = (u16*)alloc((size_t)DIN * DMID * 2);
    u16* wlo_in   = (u16*)alloc((size_t)DIN * DMID * 2);
    u16* whi_mid  = (u16*)alloc((size_t)NMID * DMID * DMID * 2);
    u16* wlo_mid  = (u16*)alloc((size_t)NMID * DMID * DMID * 2);
    u16* whi_out  = (u16*)alloc((size_t)DMID * DOUT * 2);
    u16* wlo_out  = (u16*)alloc((size_t)DMID * DOUT * 2);
    u16* xhi      = (u16*)alloc((size_t)NN * DMID * 2);
    u16* xlo      = (u16*)alloc((size_t)NN * DMID * 2);
    u16* gs       = (u16*)alloc((size_t)8 * (NN + 1) * 32 * 2);  // sliced g
    float* vs     = (float*)alloc((size_t)NN * DMID * 4);        // pre-LN v, sliced
    float* part   = (float*)alloc((size_t)8 * NN * 2 * 4);       // [slice][node]{2}

    hipMemsetAsync(counts, 0, (size_t)NN * 4, stream);
    hipMemsetAsync(hist, 0, (size_t)MAXD * 4, stream);

    const int EB4 = (NE / 4 + 255) / 256;       // 1563
    const int NBK = (NN + 255) / 256;           // 196
    rank_kernel<<<EB4, 256, 0, stream>>>(ei, counts, rank);
    dinv_kernel<<<NBK, 256, 0, stream>>>(counts, dinv);
    hist_kernel<<<NBK, 256, 0, stream>>>(counts, hist);
    boff_kernel<<<1, 1024, 0, stream>>>(hist, binoff);
    psort_kernel<<<NBK, 256, 0, stream>>>(counts, binoff, perm, posv, degp);
    ptail_kernel<<<1, 64, 0, stream>>>(perm, degp);
    gcap_kernel<<<(NG16 + 255) / 256, 256, 0, stream>>>(degp, gcap);
    gscan_kernel<<<1, 1024, 0, stream>>>(gcap, gbase);
    escat_kernel<<<EB4, 256, 0, stream>>>(ei, rank, posv, gbase, esrc);
    zsent_kernel<<<1, 256, 0, stream>>>(gs);

    wsplit_kernel<<<(DIN * DMID + 255) / 256, 256, 0, stream>>>(W_in, whi_in, wlo_in, DIN, DMID);
    for (int i = 0; i < NMID; ++i)
        wsplit_kernel<<<(DMID * DMID + 255) / 256, 256, 0, stream>>>(
            W_mid + (size_t)i * DMID * DMID, whi_mid + (size_t)i * DMID * DMID,
            wlo_mid + (size_t)i * DMID * DMID, DMID, DMID);
    wsplit_kernel<<<(DMID * DOUT + 255) / 256, 256, 0, stream>>>(W_out, whi_out, wlo_out, DMID, DOUT);
    xsplit_kernel<<<1024, 256, 0, stream>>>(x_in, xhi, xlo);

    const int GB = (NN + 127) / 128;            // 391 (8 waves/block)
    const int AGM = (NG16 / 4) * 8;             // 6256: 8 slices x 782 group-quads
    const int AGF = (NG16 / 4) * 4;             // 3128: 4 slices
    const int LNB = NN / 4;                     // 12500

    // layer 0: 128 -> 256
    gemm_kernel<DIN, DMID><<<GB, 512, 0, stream>>>(xhi, xlo, whi_in, wlo_in, dinv, gs);
    agg_kernel<DMID, false><<<AGM, 256, 0, stream>>>(gs, esrc, gbase, perm, degp,
                                                     dinv, b_in, vs, part, nullptr);
    ln_kernel<<<LNB, 256, 0, stream>>>(vs, part, gamma, beta, xhi, xlo);
    // 8 mid layers: 256 -> 256
    for (int i = 0; i < NMID; ++i) {
        gemm_kernel<DMID, DMID><<<GB, 512, 0, stream>>>(xhi, xlo,
                                                        whi_mid + (size_t)i * DMID * DMID,
                                                        wlo_mid + (size_t)i * DMID * DMID,
                                                        dinv, gs);
        agg_kernel<DMID, false><<<AGM, 256, 0, stream>>>(gs, esrc, gbase, perm, degp,
                                                         dinv, b_mid + (size_t)i * DMID,
                                                         vs, part, nullptr);
        ln_kernel<<<LNB, 256, 0, stream>>>(vs, part,
                                           gamma + (size_t)(i + 1) * DMID,
                                           beta + (size_t)(i + 1) * DMID, xhi, xlo);
    }
    // final layer: 256 -> 128, no LN/SiLU; writes fp32 out directly
    gemm_kernel<DMID, DOUT><<<GB, 512, 0, stream>>>(xhi, xlo, whi_out, wlo_out, dinv, gs);
    agg_kernel<DOUT, true><<<AGF, 256, 0, stream>>>(gs, esrc, gbase, perm, degp,
                                                    dinv, b_out, nullptr, nullptr,
                                                    (float*)d_out);
}

// Round 6
// 1487.129 us; speedup vs baseline: 1.8449x; 1.1137x over previous
//
#include <hip/hip_runtime.h>
#include <stdint.h>

#define NN   50000
#define NE   1600000
#define DIN  128
#define DMID 256
#define DOUT 128
#define NMID 8
#define MAXD 2048                 // esrc capacity slack term (kept from r4/r5)
#define NBIN 128                  // degree bins (true max deg ~75, clamp safe)
#define NBKB 196                  // hist/psort node-partition blocks = ceil(NN/256)
#define NG16 3128                 // 16-node groups (3125 real + 3 pad), %4==0
#define NNP  (NG16 * 16)          // 50048: perm padded with sentinel NN
#define ECAP (NE + 64 * MAXD)     // transposed edge-slot capacity (sorted bound)

#define AS1 __attribute__((address_space(1)))
#define AS3 __attribute__((address_space(3)))

typedef unsigned short u16;
typedef unsigned int   u32;
typedef __attribute__((ext_vector_type(8))) short short8;
typedef __attribute__((ext_vector_type(4))) float f32x4;
typedef __attribute__((ext_vector_type(2))) float f32x2;
typedef __attribute__((ext_vector_type(4))) int i32x4;

__device__ __forceinline__ float bf2f(u32 u) {
    union { u32 i; float f; } c; c.i = u << 16; return c.f;
}
__device__ __forceinline__ float ubf_lo(u32 v) {
    union { u32 i; float f; } c; c.i = v << 16; return c.f;
}
__device__ __forceinline__ float ubf_hi(u32 v) {
    union { u32 i; float f; } c; c.i = v & 0xffff0000u; return c.f;
}
__device__ __forceinline__ u16 f2bf(float f) {
    union { float f; u32 i; } c; c.f = f;
    u32 u = c.i;
    return (u16)((u + 0x7fffu + ((u >> 16) & 1u)) >> 16);
}
__device__ __forceinline__ void split2(float v, u16& hi, u16& lo) {
    hi = f2bf(v);
    float r = v - bf2f(hi);
    lo = f2bf(r);
}

// ---------------- preprocessing ----------------
// pass 1: per-edge rank within its dst bucket; counts[] = true degree after.
__global__ void rank_kernel(const int* __restrict__ ei, int* __restrict__ counts,
                            int* __restrict__ rank) {
    int i = (blockIdx.x * blockDim.x + threadIdx.x) * 4;
    if (i < NE) {
        i32x4 d = *(const i32x4*)(ei + NE + i);
        i32x4 r;
        r.x = atomicAdd(&counts[d.x], 1);
        r.y = atomicAdd(&counts[d.y], 1);
        r.z = atomicAdd(&counts[d.z], 1);
        r.w = atomicAdd(&counts[d.w], 1);
        *(i32x4*)(rank + i) = r;
    }
}

// -------- two-level counting sort (r5: grid-wide return-value atomics on ~60
// degree bins serialized cross-XCD -> psort was 92 us at 0.02% VALU; replace
// with per-block LDS histograms + tiny scan; zero global atomics). --------

// (a) per-block LDS histogram -> bcnt[block][bin]
__global__ __launch_bounds__(256) void hist2_kernel(const int* __restrict__ counts,
                                                    int* __restrict__ bcnt) {
    __shared__ int h[NBIN];
    const int t = threadIdx.x;
    if (t < NBIN) h[t] = 0;
    __syncthreads();
    int i = blockIdx.x * 256 + t;
    if (i < NN) {
        int d = counts[i];
        atomicAdd(&h[d < NBIN ? d : NBIN - 1], 1);
    }
    __syncthreads();
    if (t < NBIN) bcnt[blockIdx.x * NBIN + t] = h[t];
}

// (b) bbase[k][b] = sum_{b'>b} S[b'] + sum_{k'<k} bcnt[k'][b]
//     (descending-degree-major, block-minor placement)
__global__ __launch_bounds__(128) void bscan_kernel(const int* __restrict__ bcnt,
                                                    int* __restrict__ bbase) {
    __shared__ int B[NBIN];
    const int b = threadIdx.x;      // one thread per bin
    int run = 0;
    for (int k = 0; k < NBKB; ++k) {
        bbase[k * NBIN + b] = run;  // within-bin prefix across blocks
        run += bcnt[k * NBIN + b];
    }
    __shared__ int S[NBIN];
    S[b] = run;
    __syncthreads();
    if (b == 0) {
        int acc = 0;
        for (int x = NBIN - 1; x >= 0; --x) { B[x] = acc; acc += S[x]; }
    }
    __syncthreads();
    const int add = B[b];
    for (int k = 0; k < NBKB; ++k) bbase[k * NBIN + b] += add;
}

// (c) local rank via LDS atomic (same node partition as hist2) -> final slot.
__global__ __launch_bounds__(256) void psort2_kernel(const int* __restrict__ counts,
                                                     const int* __restrict__ bbase,
                                                     int* __restrict__ perm,
                                                     int* __restrict__ posv,
                                                     int* __restrict__ degp,
                                                     float* __restrict__ dinv) {
    __shared__ int h[NBIN];
    const int t = threadIdx.x;
    if (t < NBIN) h[t] = 0;
    __syncthreads();
    int i = blockIdx.x * 256 + t;
    int d = 0, b = 0, r = 0;
    if (i < NN) {
        d = counts[i];
        b = d < NBIN ? d : NBIN - 1;
        r = atomicAdd(&h[b], 1);
    }
    __syncthreads();
    if (i < NN) {
        int pos = bbase[blockIdx.x * NBIN + b] + r;
        perm[pos] = i;
        posv[i] = pos;
        degp[pos] = d;
        dinv[i] = rsqrtf((float)d + 1.0f);
    }
}

// pad perm tail with sentinel node NN (zero row in gs), degree 0.
__global__ void ptail_kernel(int* __restrict__ perm, int* __restrict__ degp) {
    int i = NN + threadIdx.x;
    if (i < NNP) { perm[i] = NN; degp[i] = 0; }
}

// per-group (16 nodes) max degree = transposed edge-slot rows for that group.
__global__ void gcap_kernel(const int* __restrict__ degp, int* __restrict__ gcap) {
    int g = blockIdx.x * blockDim.x + threadIdx.x;
    if (g < NG16) {
        int m = 0;
        for (int j = 0; j < 16; ++j) {
            int d = degp[g * 16 + j];
            m = d > m ? d : m;
        }
        gcap[g] = m;
    }
}

// exclusive prefix of gcap*16 -> gbase (u16-slot units)
__global__ __launch_bounds__(1024) void gscan_kernel(const int* __restrict__ gcap,
                                                     int* __restrict__ gbase) {
    __shared__ int sh[1024];
    const int t = threadIdx.x;
    int loc[4];
    int s = 0;
#pragma unroll
    for (int j = 0; j < 4; ++j) {
        int idx = t * 4 + j;
        int v = (idx < NG16) ? gcap[idx] * 16 : 0;
        loc[j] = s;
        s += v;
    }
    sh[t] = s;
    __syncthreads();
    for (int offs = 1; offs < 1024; offs <<= 1) {
        int x = (t >= offs) ? sh[t - offs] : 0;
        __syncthreads();
        sh[t] += x;
        __syncthreads();
    }
    int base = (t == 0) ? 0 : sh[t - 1];
#pragma unroll
    for (int j = 0; j < 4; ++j) {
        int idx = t * 4 + j;
        if (idx < NG16) gbase[idx] = base + loc[j];
    }
}

// pass 2: scatter src ids into group-transposed slots: esrc[gbase[g] + r*16 + slot].
__global__ void escat_kernel(const int* __restrict__ ei, const int* __restrict__ rank,
                             const int* __restrict__ posv, const int* __restrict__ gbase,
                             u16* __restrict__ esrc) {
    int i = (blockIdx.x * blockDim.x + threadIdx.x) * 4;
    if (i < NE) {
        i32x4 d = *(const i32x4*)(ei + NE + i);
        i32x4 s = *(const i32x4*)(ei + i);
        i32x4 r = *(const i32x4*)(rank + i);
        { int p = posv[d.x]; esrc[gbase[p >> 4] + r.x * 16 + (p & 15)] = (u16)s.x; }
        { int p = posv[d.y]; esrc[gbase[p >> 4] + r.y * 16 + (p & 15)] = (u16)s.y; }
        { int p = posv[d.z]; esrc[gbase[p >> 4] + r.z * 16 + (p & 15)] = (u16)s.z; }
        { int p = posv[d.w]; esrc[gbase[p >> 4] + r.w * 16 + (p & 15)] = (u16)s.w; }
    }
}

// zero the sentinel row (node NN) of each of the 8 slices of gs.
__global__ void zsent_kernel(u16* __restrict__ gs) {
    int s = threadIdx.x >> 5, c = threadIdx.x & 31;
    gs[((size_t)s * (NN + 1) + NN) * 32 + c] = 0;
}

// W [K x Dc] fp32 row-major -> slice-major bf16 split: Whi[((k/32)*Dc + d)*32 + k%32]
__global__ void wsplit_kernel(const float* __restrict__ W, u16* __restrict__ Whi,
                              u16* __restrict__ Wlo, int K, int Dc) {
    int idx = blockIdx.x * blockDim.x + threadIdx.x;
    if (idx < K * Dc) {
        int k = idx / Dc, d = idx - k * Dc;
        u16 hi, lo;
        split2(W[idx], hi, lo);
        size_t o = ((size_t)(k >> 5) * Dc + d) * 32 + (k & 31);
        Whi[o] = hi;
        Wlo[o] = lo;
    }
}

// x [NN][128] fp32 -> row-major bf16 hi/lo
__global__ void xsplit_kernel(const float* __restrict__ x, u16* __restrict__ xhi,
                              u16* __restrict__ xlo) {
    int i = blockIdx.x * blockDim.x + threadIdx.x;
    int stride = gridDim.x * blockDim.x;
    for (; i < NN * DIN; i += stride) {
        u16 hi, lo;
        split2(x[i], hi, lo);
        xhi[i] = hi;
        xlo[i] = lo;
    }
}

// ---------------- GEMM: gs = sliced((x @ W) * dinv[row]) -------------------
// gs layout: [slice][node(+1)][32] bf16 — feature-column-blocked so the agg
// gather per slice has a 3.2 MB working set (fits one XCD's 4 MB L2).
template <int K, int Dc>
__global__ __launch_bounds__(512, 4) void gemm_kernel(const u16* __restrict__ xhi,
                                                      const u16* __restrict__ xlo,
                                                      const u16* __restrict__ whi,
                                                      const u16* __restrict__ wlo,
                                                      const float* __restrict__ dinv,
                                                      u16* __restrict__ gs) {
    constexpr int NTW = Dc / 32;
    constexpr int KS = K / 32;
    __shared__ u16 bh[Dc * 32];
    __shared__ u16 bl[Dc * 32];
    const int tid = threadIdx.x;
    const int wid = tid >> 6;
    const int rowPanel = wid >> 1;
    const int colPanel = wid & 1;
    const int lane = tid & 63;
    const int m = lane & 15, quad = lane >> 4;
    const int rowBase = blockIdx.x * 128 + rowPanel * 32;

    f32x4 acc[2][NTW];
#pragma unroll
    for (int rg = 0; rg < 2; ++rg)
#pragma unroll
        for (int t = 0; t < NTW; ++t) acc[rg][t] = (f32x4){0.f, 0.f, 0.f, 0.f};

    size_t arow[2];
#pragma unroll
    for (int rg = 0; rg < 2; ++rg) {
        int rowA = rowBase + rg * 16 + m;
        if (rowA > NN - 1) rowA = NN - 1;
        arow[rg] = (size_t)rowA * K + quad * 8;
    }

    for (int ks = 0; ks < KS; ++ks) {
        const u16* sh_src = whi + (size_t)ks * Dc * 32;
        const u16* sl_src = wlo + (size_t)ks * Dc * 32;
        __syncthreads();
#pragma unroll
        for (int i = 0; i < Dc * 4; i += 512) {
            int j = i + tid;
            __builtin_amdgcn_global_load_lds((const AS1 void*)(sh_src + j * 8),
                                             (AS3 void*)((AS3 u16*)bh + j * 8), 16, 0, 0);
            __builtin_amdgcn_global_load_lds((const AS1 void*)(sl_src + j * 8),
                                             (AS3 void*)((AS3 u16*)bl + j * 8), 16, 0, 0);
        }
        short8 ah[2], al[2];
#pragma unroll
        for (int rg = 0; rg < 2; ++rg) {
            ah[rg] = *(const short8*)(xhi + arow[rg] + ks * 32);
            al[rg] = *(const short8*)(xlo + arow[rg] + ks * 32);
        }
        __syncthreads();
#pragma unroll
        for (int t = 0; t < NTW; ++t) {
            const int bo = ((colPanel * NTW + t) * 16 + m) * 32 + quad * 8;
            short8 wh = *(const short8*)(bh + bo);
            short8 wl = *(const short8*)(bl + bo);
#pragma unroll
            for (int rg = 0; rg < 2; ++rg) {
                acc[rg][t] = __builtin_amdgcn_mfma_f32_16x16x32_bf16(ah[rg], wh, acc[rg][t], 0, 0, 0);
                acc[rg][t] = __builtin_amdgcn_mfma_f32_16x16x32_bf16(al[rg], wh, acc[rg][t], 0, 0, 0);
                acc[rg][t] = __builtin_amdgcn_mfma_f32_16x16x32_bf16(ah[rg], wl, acc[rg][t], 0, 0, 0);
            }
        }
    }

#pragma unroll
    for (int rg = 0; rg < 2; ++rg) {
        const int r0 = rowBase + rg * 16 + quad * 4;
        float dv[4];
#pragma unroll
        for (int r = 0; r < 4; ++r) {
            int rr = r0 + r;
            dv[r] = (rr < NN) ? dinv[rr] : 0.f;
        }
#pragma unroll
        for (int t = 0; t < NTW; ++t) {
            const int col = colPanel * (Dc / 2) + t * 16 + m;
#pragma unroll
            for (int r = 0; r < 4; ++r) {
                int rr = r0 + r;
                if (rr < NN) {
                    size_t o = ((size_t)(col >> 5) * (NN + 1) + rr) * 32 + (col & 31);
                    gs[o] = f2bf(acc[rg][t][r] * dv[r]);
                }
            }
        }
    }
}

// ---------------- sliced aggregation v5: quad-cooperative rows ---------------
// Block = (slice, 4 degree-sorted 16-node groups), slice = blockIdx & (NSL-1)
// -> each XCD gathers only its own 3.2 MB slice (L2-resident; proven r2-r4).
// Wave = 16 node-slots x 4 quarters: the 4 lanes of a quad read the 4
// consecutive 16B quarters of the SAME row -> 1 cache-line request per row.

template <int Dc, bool FINAL>
__global__ __launch_bounds__(256, 8) void agg_kernel(const u16* __restrict__ gs,
                                                     const u16* __restrict__ esrc,
                                                     const int* __restrict__ gbase,
                                                     const int* __restrict__ perm,
                                                     const int* __restrict__ degp,
                                                     const float* __restrict__ dinv,
                                                     const float* __restrict__ bias,
                                                     float* __restrict__ vs,
                                                     float* __restrict__ part,
                                                     float* __restrict__ outf) {
    constexpr int NSL = Dc / 32;
    constexpr int SH = (NSL == 8) ? 3 : 2;
    const int slice = blockIdx.x & (NSL - 1);
    const int grp4 = blockIdx.x >> SH;
    const int wid = threadIdx.x >> 6, lane = threadIdx.x & 63;
    const int grp = grp4 * 4 + wid;          // 16-node group id
    const int nslot = lane >> 2, q = lane & 3;
    const int gpos = grp * 16 + nslot;       // perm index
    const int node = perm[gpos];             // NN for padding lanes
    const int deg = degp[gpos];

    const u16* gslb = gs + (size_t)slice * (NN + 1) * 32 + q * 8;  // quarter base
    const u16* ep = esrc + gbase[grp] + nslot;

    float a[8];
#pragma unroll
    for (int j = 0; j < 8; ++j) a[j] = 0.f;

    // self row first (sentinel node NN reads the zero row)
    uint4 A = *(const uint4*)(gslb + (size_t)node * 32);
    int sNxt = (deg > 0) ? (int)ep[0] : node;
    int t = 0;
    for (;;) {
        uint4 B = *(const uint4*)(gslb + (size_t)sNxt * 32);        // next row in flight
        int sN2 = (t + 1 < deg) ? (int)ep[(t + 1) * 16] : sNxt;     // next src in flight
        a[0] += ubf_lo(A.x); a[1] += ubf_hi(A.x);                   // consume current
        a[2] += ubf_lo(A.y); a[3] += ubf_hi(A.y);
        a[4] += ubf_lo(A.z); a[5] += ubf_hi(A.z);
        a[6] += ubf_lo(A.w); a[7] += ubf_hi(A.w);
        ++t;
        if (t > deg) break;                                         // self + deg rows
        A = B;
        sNxt = sN2;
    }

    if (node < NN) {
        const float dv = dinv[node];
        const int f = slice * 32 + q * 8;
        float v[8];
        f32x4 b0 = *(const f32x4*)(bias + f);
        f32x4 b1 = *(const f32x4*)(bias + f + 4);
#pragma unroll
        for (int j = 0; j < 4; ++j) v[j] = a[j] * dv + b0[j];
#pragma unroll
        for (int j = 0; j < 4; ++j) v[j + 4] = a[j + 4] * dv + b1[j];

        if (FINAL) {
            float* op = outf + (size_t)node * Dc + f;
            *(f32x4*)op = (f32x4){v[0], v[1], v[2], v[3]};
            *(f32x4*)(op + 4) = (f32x4){v[4], v[5], v[6], v[7]};
        } else {
            float* vp = vs + ((size_t)slice * NN + node) * 32 + q * 8;
            *(f32x4*)vp = (f32x4){v[0], v[1], v[2], v[3]};
            *(f32x4*)(vp + 4) = (f32x4){v[4], v[5], v[6], v[7]};
            float p1 = 0.f, p2 = 0.f;
#pragma unroll
            for (int j = 0; j < 8; ++j) {
                p1 += v[j];
                p2 += v[j] * v[j];
            }
            // quad reduction (4 lanes of this node)
            p1 += __shfl_xor(p1, 1, 64); p2 += __shfl_xor(p2, 1, 64);
            p1 += __shfl_xor(p1, 2, 64); p2 += __shfl_xor(p2, 2, 64);
            // part[slice][node]: per-XCD-contiguous -> no cross-XCD false sharing
            if (q == 0)
                *(f32x2*)(part + ((size_t)slice * NN + node) * 2) = (f32x2){p1, p2};
        }
    }
}

// ---------------- LN + SiLU + bf16 hi/lo split (streaming) -------------------
// wave per node; lane owns 4 consecutive features. Reads sliced v + partials.
__global__ __launch_bounds__(256) void ln_kernel(const float* __restrict__ vs,
                                                 const float* __restrict__ part,
                                                 const float* __restrict__ gamma,
                                                 const float* __restrict__ beta,
                                                 u16* __restrict__ xhi,
                                                 u16* __restrict__ xlo) {
    const int wid = threadIdx.x >> 6, lane = threadIdx.x & 63;
    const int node = blockIdx.x * 4 + wid;
    const int s = lane >> 3, o = (lane & 7) * 4;

    f32x4 vv = *(const f32x4*)(vs + ((size_t)s * NN + node) * 32 + o);
    f32x2 p = *(const f32x2*)(part + ((size_t)(lane & 7) * NN + node) * 2);
    float s1 = p.x, s2 = p.y;
    s1 += __shfl_xor(s1, 1, 64); s2 += __shfl_xor(s2, 1, 64);
    s1 += __shfl_xor(s1, 2, 64); s2 += __shfl_xor(s2, 2, 64);
    s1 += __shfl_xor(s1, 4, 64); s2 += __shfl_xor(s2, 4, 64);

    const float mu = s1 * (1.f / 256.f);
    const float var = s2 * (1.f / 256.f) - mu * mu;
    const float rstd = rsqrtf(fmaxf(var, 0.f) + 1e-5f);

    const int f = s * 32 + o;
    u16 hh[4], ll[4];
#pragma unroll
    for (int j = 0; j < 4; ++j) {
        float y = (vv[j] - mu) * rstd * gamma[f + j] + beta[f + j];
        y = y / (1.f + __expf(-y));
        split2(y, hh[j], ll[j]);
    }
    uint2 oh, ol;
    oh.x = (u32)hh[0] | ((u32)hh[1] << 16);
    oh.y = (u32)hh[2] | ((u32)hh[3] << 16);
    ol.x = (u32)ll[0] | ((u32)ll[1] << 16);
    ol.y = (u32)ll[2] | ((u32)ll[3] << 16);
    *(uint2*)(xhi + (size_t)node * 256 + f) = oh;
    *(uint2*)(xlo + (size_t)node * 256 + f) = ol;
}

// ---------------- launcher ----------------

extern "C" void kernel_launch(void* const* d_in, const int* in_sizes, int n_in,
                              void* d_out, int out_size, void* d_ws, size_t ws_size,
                              hipStream_t stream) {
    (void)in_sizes; (void)n_in; (void)out_size; (void)ws_size;
    const float* x_in  = (const float*)d_in[0];
    const int*   ei    = (const int*)d_in[1];
    const float* W_in  = (const float*)d_in[2];
    const float* b_in  = (const float*)d_in[3];
    const float* W_mid = (const float*)d_in[4];
    const float* b_mid = (const float*)d_in[5];
    const float* W_out = (const float*)d_in[6];
    const float* b_out = (const float*)d_in[7];
    const float* gamma = (const float*)d_in[8];
    const float* beta  = (const float*)d_in[9];

    char* ws = (char*)d_ws;
    size_t off = 0;
    auto alloc = [&](size_t bytes) -> char* {
        char* p = ws + off;
        off += (bytes + 255) & ~(size_t)255;
        return p;
    };
    float* dinv   = (float*)alloc((size_t)NN * 4);
    int* counts   = (int*)alloc((size_t)NN * 4);
    int* rank     = (int*)alloc((size_t)NE * 4);
    int* bcnt     = (int*)alloc((size_t)NBKB * NBIN * 4);
    int* bbase    = (int*)alloc((size_t)NBKB * NBIN * 4);
    int* perm     = (int*)alloc((size_t)NNP * 4);
    int* posv     = (int*)alloc((size_t)NN * 4);
    int* degp     = (int*)alloc((size_t)NNP * 4);
    int* gcap     = (int*)alloc((size_t)NG16 * 4);
    int* gbase    = (int*)alloc((size_t)NG16 * 4);
    u16* esrc     = (u16*)alloc((size_t)ECAP * 2);
    u16* whi_in   = (u16*)alloc((size_t)DIN * DMID * 2);
    u16* wlo_in   = (u16*)alloc((size_t)DIN * DMID * 2);
    u16* whi_mid  = (u16*)alloc((size_t)NMID * DMID * DMID * 2);
    u16* wlo_mid  = (u16*)alloc((size_t)NMID * DMID * DMID * 2);
    u16* whi_out  = (u16*)alloc((size_t)DMID * DOUT * 2);
    u16* wlo_out  = (u16*)alloc((size_t)DMID * DOUT * 2);
    u16* xhi      = (u16*)alloc((size_t)NN * DMID * 2);
    u16* xlo      = (u16*)alloc((size_t)NN * DMID * 2);
    u16* gs       = (u16*)alloc((size_t)8 * (NN + 1) * 32 * 2);  // sliced g
    float* vs     = (float*)alloc((size_t)NN * DMID * 4);        // pre-LN v, sliced
    float* part   = (float*)alloc((size_t)8 * NN * 2 * 4);       // [slice][node]{2}

    hipMemsetAsync(counts, 0, (size_t)NN * 4, stream);

    const int EB4 = (NE / 4 + 255) / 256;       // 1563
    rank_kernel<<<EB4, 256, 0, stream>>>(ei, counts, rank);
    hist2_kernel<<<NBKB, 256, 0, stream>>>(counts, bcnt);
    bscan_kernel<<<1, 128, 0, stream>>>(bcnt, bbase);
    psort2_kernel<<<NBKB, 256, 0, stream>>>(counts, bbase, perm, posv, degp, dinv);
    ptail_kernel<<<1, 64, 0, stream>>>(perm, degp);
    gcap_kernel<<<(NG16 + 255) / 256, 256, 0, stream>>>(degp, gcap);
    gscan_kernel<<<1, 1024, 0, stream>>>(gcap, gbase);
    escat_kernel<<<EB4, 256, 0, stream>>>(ei, rank, posv, gbase, esrc);
    zsent_kernel<<<1, 256, 0, stream>>>(gs);

    wsplit_kernel<<<(DIN * DMID + 255) / 256, 256, 0, stream>>>(W_in, whi_in, wlo_in, DIN, DMID);
    for (int i = 0; i < NMID; ++i)
        wsplit_kernel<<<(DMID * DMID + 255) / 256, 256, 0, stream>>>(
            W_mid + (size_t)i * DMID * DMID, whi_mid + (size_t)i * DMID * DMID,
            wlo_mid + (size_t)i * DMID * DMID, DMID, DMID);
    wsplit_kernel<<<(DMID * DOUT + 255) / 256, 256, 0, stream>>>(W_out, whi_out, wlo_out, DMID, DOUT);
    xsplit_kernel<<<1024, 256, 0, stream>>>(x_in, xhi, xlo);

    const int GB = (NN + 127) / 128;            // 391 (8 waves/block)
    const int AGM = (NG16 / 4) * 8;             // 6256: 8 slices x 782 group-quads
    const int AGF = (NG16 / 4) * 4;             // 3128: 4 slices
    const int LNB = NN / 4;                     // 12500

    // layer 0: 128 -> 256
    gemm_kernel<DIN, DMID><<<GB, 512, 0, stream>>>(xhi, xlo, whi_in, wlo_in, dinv, gs);
    agg_kernel<DMID, false><<<AGM, 256, 0, stream>>>(gs, esrc, gbase, perm, degp,
                                                     dinv, b_in, vs, part, nullptr);
    ln_kernel<<<LNB, 256, 0, stream>>>(vs, part, gamma, beta, xhi, xlo);
    // 8 mid layers: 256 -> 256
    for (int i = 0; i < NMID; ++i) {
        gemm_kernel<DMID, DMID><<<GB, 512, 0, stream>>>(xhi, xlo,
                                                        whi_mid + (size_t)i * DMID * DMID,
                                                        wlo_mid + (size_t)i * DMID * DMID,
                                                        dinv, gs);
        agg_kernel<DMID, false><<<AGM, 256, 0, stream>>>(gs, esrc, gbase, perm, degp,
                                                         dinv, b_mid + (size_t)i * DMID,
                                                         vs, part, nullptr);
        ln_kernel<<<LNB, 256, 0, stream>>>(vs, part,
                                           gamma + (size_t)(i + 1) * DMID,
                                           beta + (size_t)(i + 1) * DMID, xhi, xlo);
    }
    // final layer: 256 -> 128, no LN/SiLU; writes fp32 out directly
    gemm_kernel<DMID, DOUT><<<GB, 512, 0, stream>>>(xhi, xlo, whi_out, wlo_out, dinv, gs);
    agg_kernel<DOUT, true><<<AGF, 256, 0, stream>>>(gs, esrc, gbase, perm, degp,
                                                    dinv, b_out, nullptr, nullptr,
                                                    (float*)d_out);
}